// Round 9
// baseline (2803.306 us; speedup 1.0000x reference)
//
#include <hip/hip_runtime.h>
#include <stdint.h>

#define B_ 16
#define S_ 2048
#define F_ 129
#define H_ 128
#define G_ 512   // 4*H

typedef float f32x4 __attribute__((ext_vector_type(4)));
typedef float f32x2 __attribute__((ext_vector_type(2)));
typedef short s16x8 __attribute__((ext_vector_type(8)));
typedef _Float16 f16x8 __attribute__((ext_vector_type(8)));

// LDS-only barrier: waits ds ops, does NOT drain vmcnt (global loads/stores
// stay in flight across it). __syncthreads() emits s_waitcnt vmcnt(0).
#define BAR_LDS() __asm__ volatile("s_waitcnt lgkmcnt(0)\n\ts_barrier" ::: "memory")

__device__ inline unsigned short f2bf(float f) {
  union { float f; unsigned u; } v; v.f = f;
  unsigned u = v.u;
  unsigned r = (u + 0x7FFFu + ((u >> 16) & 1u)) >> 16;
  return (unsigned short)r;
}

__device__ inline float rcp_(float x) { return __builtin_amdgcn_rcpf(x); }

__device__ inline float sigmoid_fast(float x) { return rcp_(1.f + __expf(-x)); }

// branchless tanh: 1 - 2/(1+e^{2x})
__device__ inline float tanh_fast(float x) {
  return 1.f - 2.f * rcp_(1.f + __expf(2.f * x));
}

// ---------------------------------------------------------------------------
// xg[b,s,g] = sum_f x[b,s,f] * W_ih[g,f] + (b_ih[g] + b_hh[g])
// b_hh folded here so the LSTM inner loop never touches it (R9).
// ---------------------------------------------------------------------------
__global__ __launch_bounds__(256) void xg_kernel(const float* __restrict__ x,
    const float* __restrict__ W_ih, const float* __restrict__ b_ih,
    const float* __restrict__ b_hh, float* __restrict__ xg) {
  __shared__ __align__(16) float xs[64 * 132];
  __shared__ __align__(16) float ws[32 * 132];
  int tid = threadIdx.x;
  long R0 = (long)blockIdx.x * 64;
  for (int i = tid; i < 64 * 129; i += 256) {
    int r = i / 129, c = i - r * 129;
    xs[r * 132 + c] = x[R0 * 129 + i];
  }
  int cl = tid & 31, rg = tid >> 5;
  int r0 = rg * 8;
  for (int ch = 0; ch < 16; ++ch) {
    __syncthreads();
    for (int i = tid; i < 32 * 129; i += 256) {
      int r = i / 129, c = i - r * 129;
      ws[r * 132 + c] = W_ih[(ch * 32 + r) * 129 + c];
    }
    __syncthreads();
    int gcol = ch * 32 + cl;
    float bias = b_ih[gcol] + b_hh[gcol];
    float acc[8];
    #pragma unroll
    for (int rr = 0; rr < 8; ++rr) acc[rr] = bias;
    const float* wr = &ws[cl * 132];
    #pragma unroll 8
    for (int k = 0; k < 128; k += 4) {
      f32x4 w4 = *(const f32x4*)&wr[k];
      #pragma unroll
      for (int rr = 0; rr < 8; ++rr) {
        f32x4 x4 = *(const f32x4*)&xs[(r0 + rr) * 132 + k];
        acc[rr] += x4.x * w4.x + x4.y * w4.y + x4.z * w4.z + x4.w * w4.w;
      }
    }
    float wl = wr[128];
    #pragma unroll
    for (int rr = 0; rr < 8; ++rr) {
      acc[rr] += xs[(r0 + rr) * 132 + 128] * wl;
      xg[(R0 + r0 + rr) * G_ + gcol] = acc[rr];
    }
  }
}

// ---------------------------------------------------------------------------
// RBF: kf[row] = exp(-sum_f (x-p)^2), one wave per row.
// ---------------------------------------------------------------------------
__global__ __launch_bounds__(256) void rbf_kernel(const float* __restrict__ x,
    const float* __restrict__ p, float* __restrict__ kf) {
  int wave = threadIdx.x >> 6, lane = threadIdx.x & 63;
  long row = (long)blockIdx.x * 4 + wave;
  const float* xr = x + row * F_;
  const float* pr = p + row * F_;
  float ss = 0.f;
  for (int k = lane; k < F_; k += 64) { float d = xr[k] - pr[k]; ss += d * d; }
  #pragma unroll
  for (int off = 32; off; off >>= 1) ss += __shfl_xor(ss, off, 64);
  if (lane == 0) kf[row] = __expf(-ss);
}

// ---------------------------------------------------------------------------
// LSTM scan, round 9: batched across M. All 16 batches share W_hh, so step t
// is ONE M=16 GEMM: H_t(16x128) . W_hh^T -> one block, 8 waves, 1 CU.
// Wave w owns the 4 gate tiles {ty*8+w} (all 4 types of units 16w..16w+15):
// 16 MFMA/wave/step, weights resident f16 (same as R7).
// Lane roles per MFMA spec: A-read m=lane&15 = BATCH, k=quad*8; C rows
// quad*4+reg = BATCH, col=lane&15 = unit; so each lane's epilogue updates 4
// distinct (batch,unit) pairs -> ZERO redundancy (R7/R8 were 4x redundant and
// ran the full matvec on 16 CUs with 1 real M-row).
// h exchange: hbuf[2][16*136] f16 (stride 136 halfs: b128 reads at the 8-clk
// LDS bandwidth floor). BAR_LDS + one-step-delayed qbf stores kept. b_hh
// pre-folded into xg. xg reads: 16 dword loads/lane/step (64B-run coalesced),
// prefetch depth 2.
// ---------------------------------------------------------------------------
__global__ __launch_bounds__(512, 2) void lstm_kernel(const float* __restrict__ xg,
    const float* __restrict__ W_hh, const float* __restrict__ b_hh,
    unsigned short* __restrict__ qbf) {
  __shared__ __align__(16) _Float16 hbuf[2][16 * 136];
  int tid = threadIdx.x;
  int w = tid >> 6, lane = tid & 63;
  int q = lane >> 4;                 // quad: C rows 4q..4q+3 (batches); A k-chunk
  int n16 = lane & 15;               // unit col within tile; ALSO A batch row
  int u = (w << 4) | n16;            // unit 0..127 owned by this lane
  (void)b_hh;                        // folded into xg
  // resident weights, f16: Wf[ty][kb] = W_hh[(ty*128+u)][kb*32+q*8 .. +8]
  f16x8 Wf[4][4];
  #pragma unroll
  for (int ty = 0; ty < 4; ++ty) {
    #pragma unroll
    for (int kb = 0; kb < 4; ++kb) {
      const float* src = &W_hh[(ty * 128 + u) * H_ + kb * 32 + q * 8];
      f16x8 v;
      #pragma unroll
      for (int j = 0; j < 8; ++j) v[j] = (_Float16)src[j];
      Wf[ty][kb] = v;
    }
  }
  for (int i = tid; i < 2 * 16 * 136; i += 512)
    ((_Float16*)hbuf)[i] = (_Float16)0.f;    // h_{-1}=0 (buf1 read at t=0)
  float c4[4] = {0.f, 0.f, 0.f, 0.f};
  const float* xb[4];
  unsigned short* qbase[4];
  #pragma unroll
  for (int r = 0; r < 4; ++r) {
    int b = 4 * q + r;
    xb[r] = xg + (long)b * S_ * G_ + u;
    qbase[r] = qbf + (long)b * S_ * H_ + u;
  }
  float cur[4][4], nxt[4][4];
  #pragma unroll
  for (int r = 0; r < 4; ++r)
    #pragma unroll
    for (int ty = 0; ty < 4; ++ty) {
      cur[r][ty] = xb[r][ty * 128];
      nxt[r][ty] = xb[r][G_ + ty * 128];
    }
  unsigned short hvp[4] = {0, 0, 0, 0};
  __syncthreads();                   // init visibility (once)
  for (int t = 0; t < S_; ++t) {
    BAR_LDS();                       // h_{t-1} LDS writes visible; no vm drain
    // A-frags: m = lane&15 = batch, k = quad*8 (per-lane distinct, 1KB/instr)
    const _Float16* hsrc = hbuf[(t + 1) & 1];
    f16x8 A[4];
    #pragma unroll
    for (int kb = 0; kb < 4; ++kb)
      A[kb] = *(const f16x8*)(hsrc + n16 * 136 + kb * 32 + q * 8);
    if (t > 0) {                     // delayed stores: full step in flight
      #pragma unroll
      for (int r = 0; r < 4; ++r) qbase[r][(long)(t - 1) * H_] = hvp[r];
    }
    long pf = (long)((t + 2 < S_) ? t + 2 : S_ - 1) * G_;
    float nn[4][4];
    #pragma unroll
    for (int r = 0; r < 4; ++r)
      #pragma unroll
      for (int ty = 0; ty < 4; ++ty) nn[r][ty] = xb[r][pf + ty * 128];
    // 4 chained MFMAs per gate type (R8 showed forced-independent is worse)
    f32x4 acc[4];
    #pragma unroll
    for (int ty = 0; ty < 4; ++ty) {
      f32x4 a;
      a[0] = 0.f; a[1] = 0.f; a[2] = 0.f; a[3] = 0.f;
      #pragma unroll
      for (int kb = 0; kb < 4; ++kb)
        a = __builtin_amdgcn_mfma_f32_16x16x32_f16(A[kb], Wf[ty][kb], a, 0, 0, 0);
      acc[ty] = a;
    }
    // epilogue: reg r = batch 4q+r, all 4 gate types local
    #pragma unroll
    for (int r = 0; r < 4; ++r) {
      float g0 = acc[0][r] + cur[r][0];
      float g1 = acc[1][r] + cur[r][1];
      float g2 = acc[2][r] + cur[r][2];
      float g3 = acc[3][r] + cur[r][3];
      float ai = sigmoid_fast(g0);
      float af = sigmoid_fast(g1);
      float ag = tanh_fast(g2);
      float ao = sigmoid_fast(g3);
      c4[r] = af * c4[r] + ai * ag;
      float hv = ao * tanh_fast(c4[r]);
      hbuf[t & 1][(4 * q + r) * 136 + u] = (_Float16)hv;
      hvp[r] = f2bf(hv);
    }
    #pragma unroll
    for (int r = 0; r < 4; ++r)
      #pragma unroll
      for (int ty = 0; ty < 4; ++ty) { cur[r][ty] = nxt[r][ty]; nxt[r][ty] = nn[r][ty]; }
  }
  #pragma unroll
  for (int r = 0; r < 4; ++r) qbase[r][(long)(S_ - 1) * H_] = hvp[r];
}

// ---------------------------------------------------------------------------
// Flash attention, scale 1/sqrt(129). 64 Q-rows per block (4 waves x 16 rows),
// KV tiles of 64, bf16 MFMA 16x16x32. Grid = 16 batches * 32 q-tiles.
// ---------------------------------------------------------------------------
__global__ __launch_bounds__(256) void attn_kernel(const unsigned short* __restrict__ qbf,
    float* __restrict__ ctx) {
  __shared__ __align__(16) unsigned short Ks[64 * 136];
  __shared__ __align__(16) unsigned short VT[128 * 72];
  __shared__ __align__(16) unsigned short Ps[4 * 16 * 72];
  int tid = threadIdx.x;
  int lane = tid & 63, w = tid >> 6;
  int b = blockIdx.x >> 5;
  int q0 = (blockIdx.x & 31) * 64;
  const unsigned short* qb = qbf + (long)b * S_ * H_;
  int l15 = lane & 15;
  int koff = (lane >> 4) * 8;
  s16x8 qfrag[4];
  #pragma unroll
  for (int kb = 0; kb < 4; ++kb)
    qfrag[kb] = *(const s16x8*)(qb + (long)(q0 + w * 16 + l15) * H_ + kb * 32 + koff);
  f32x4 oacc[8];
  #pragma unroll
  for (int n = 0; n < 8; ++n)
    #pragma unroll
    for (int r = 0; r < 4; ++r) oacc[n][r] = 0.f;
  float mrow[4], lrow[4];
  #pragma unroll
  for (int r = 0; r < 4; ++r) { mrow[r] = -1e30f; lrow[r] = 0.f; }
  const float scale = 0.08804509063256238f;  // 1/sqrt(129)
  unsigned short* Pw = &Ps[w * 16 * 72];
  for (int t = 0; t < S_ / 64; ++t) {
    {
      int rr = tid >> 4;
      int c0 = (tid & 15) * 8;
      #pragma unroll
      for (int pch = 0; pch < 4; ++pch) {
        int r = pch * 16 + rr;
        s16x8 v = *(const s16x8*)(qb + (long)(t * 64 + r) * H_ + c0);
        *(s16x8*)(&Ks[r * 136 + c0]) = v;
        #pragma unroll
        for (int i = 0; i < 8; ++i) VT[(c0 + i) * 72 + r] = (unsigned short)v[i];
      }
    }
    __syncthreads();
    f32x4 sacc[4];
    #pragma unroll
    for (int n = 0; n < 4; ++n) {
      f32x4 acc;
      #pragma unroll
      for (int r = 0; r < 4; ++r) acc[r] = 0.f;
      #pragma unroll
      for (int kb = 0; kb < 4; ++kb) {
        s16x8 bfrag = *(const s16x8*)(&Ks[(n * 16 + l15) * 136 + kb * 32 + koff]);
        acc = __builtin_amdgcn_mfma_f32_16x16x32_bf16(qfrag[kb], bfrag, acc, 0, 0, 0);
      }
      sacc[n] = acc;
    }
    #pragma unroll
    for (int r = 0; r < 4; ++r) {
      float mx = fmaxf(fmaxf(sacc[0][r], sacc[1][r]), fmaxf(sacc[2][r], sacc[3][r]));
      #pragma unroll
      for (int m = 1; m < 16; m <<= 1) mx = fmaxf(mx, __shfl_xor(mx, m, 64));
      mx *= scale;
      float mnew = fmaxf(mrow[r], mx);
      float alpha = __expf(mrow[r] - mnew);
      mrow[r] = mnew;
      float psum = 0.f;
      #pragma unroll
      for (int n = 0; n < 4; ++n) {
        float pv = __expf(sacc[n][r] * scale - mnew);
        sacc[n][r] = pv;
        psum += pv;
      }
      #pragma unroll
      for (int m = 1; m < 16; m <<= 1) psum += __shfl_xor(psum, m, 64);
      lrow[r] = lrow[r] * alpha + psum;
      #pragma unroll
      for (int n = 0; n < 8; ++n) oacc[n][r] *= alpha;
    }
    #pragma unroll
    for (int n = 0; n < 4; ++n)
      #pragma unroll
      for (int r = 0; r < 4; ++r)
        Pw[((lane >> 4) * 4 + r) * 72 + n * 16 + l15] = f2bf(sacc[n][r]);
    __syncthreads();
    #pragma unroll
    for (int kb = 0; kb < 2; ++kb) {
      s16x8 afrag = *(const s16x8*)(&Pw[l15 * 72 + kb * 32 + koff]);
      #pragma unroll
      for (int n = 0; n < 8; ++n) {
        s16x8 bfrag = *(const s16x8*)(&VT[(n * 16 + l15) * 72 + kb * 32 + koff]);
        oacc[n] = __builtin_amdgcn_mfma_f32_16x16x32_bf16(afrag, bfrag, oacc[n], 0, 0, 0);
      }
    }
    __syncthreads();
  }
  float* cb = ctx + (long)b * S_ * H_;
  #pragma unroll
  for (int n = 0; n < 8; ++n)
    #pragma unroll
    for (int r = 0; r < 4; ++r) {
      int row = q0 + w * 16 + (lane >> 4) * 4 + r;
      cb[(long)row * H_ + n * 16 + l15] = oacc[n][r] / lrow[r];
    }
}

// ---------------------------------------------------------------------------
// Fused MLP: h0=[ctx,kf] -> 4x relu(h W^T + b) -> logits -> log_softmax.
// ---------------------------------------------------------------------------
__global__ __launch_bounds__(256) void mlp_kernel(const float* __restrict__ ctx,
    const float* __restrict__ kf, const float* __restrict__ Wc,
    const float* __restrict__ bc, const float* __restrict__ Wh,
    const float* __restrict__ bh, float* __restrict__ out) {
  __shared__ __align__(16) float hb[64 * 132];
  __shared__ __align__(16) float wc[32 * 132];
  int tid = threadIdx.x;
  long R0 = (long)blockIdx.x * 64;
  for (int i = tid; i < 64 * 128; i += 256) {
    int r = i >> 7, c = i & 127;
    hb[r * 132 + c] = ctx[(R0 + r) * H_ + c];
  }
  for (int r = tid; r < 64; r += 256) hb[r * 132 + 128] = kf[R0 + r];
  int cl = tid & 31, rg = tid >> 5, r0 = rg * 8;
  for (int l = 0; l < 4; ++l) {
    float areg[5][8];
    #pragma unroll
    for (int cc = 0; cc < 5; ++cc) {
      int cbase = cc * 32;
      int ccnt = (cc < 4) ? 32 : 1;
      __syncthreads();
      for (int i = tid; i < ccnt * 129; i += 256) {
        int r = i / 129, c = i - r * 129;
        wc[r * 132 + c] = Wc[(l * 129 + cbase + r) * 129 + c];
      }
      __syncthreads();
      if (cl < ccnt) {
        float bias = bc[l * 129 + cbase + cl];
        float acc[8];
        #pragma unroll
        for (int rr = 0; rr < 8; ++rr) acc[rr] = bias;
        const float* wr = &wc[cl * 132];
        for (int k = 0; k < 128; k += 4) {
          f32x4 w4 = *(const f32x4*)&wr[k];
          #pragma unroll
          for (int rr = 0; rr < 8; ++rr) {
            f32x4 x4 = *(const f32x4*)&hb[(r0 + rr) * 132 + k];
            acc[rr] += x4.x * w4.x + x4.y * w4.y + x4.z * w4.z + x4.w * w4.w;
          }
        }
        float wl = wr[128];
        #pragma unroll
        for (int rr = 0; rr < 8; ++rr)
          areg[cc][rr] = fmaxf(acc[rr] + hb[(r0 + rr) * 132 + 128] * wl, 0.f);
      }
    }
    __syncthreads();
    #pragma unroll
    for (int cc = 0; cc < 5; ++cc) {
      int ccnt = (cc < 4) ? 32 : 1;
      if (cl < ccnt) {
        #pragma unroll
        for (int rr = 0; rr < 8; ++rr) hb[(r0 + rr) * 132 + cc * 32 + cl] = areg[cc][rr];
      }
    }
    __syncthreads();
  }
  if (tid < 64) {
    int r = tid;
    float z0 = bh[0], z1 = bh[1];
    for (int k = 0; k < 129; ++k) {
      float h = hb[r * 132 + k];
      z0 += h * Wh[k];
      z1 += h * Wh[129 + k];
    }
    float mx = fmaxf(z0, z1);
    float lse = mx + __logf(__expf(z0 - mx) + __expf(z1 - mx));
    out[(R0 + r) * 2 + 0] = z0 - lse;
    out[(R0 + r) * 2 + 1] = z1 - lse;
  }
}

extern "C" void kernel_launch(void* const* d_in, const int* in_sizes, int n_in,
                              void* d_out, int out_size, void* d_ws, size_t ws_size,
                              hipStream_t stream) {
  const float* x    = (const float*)d_in[0];
  const float* prot = (const float*)d_in[1];
  const float* W_ih = (const float*)d_in[2];
  const float* W_hh = (const float*)d_in[3];
  const float* b_ih = (const float*)d_in[4];
  const float* b_hh = (const float*)d_in[5];
  const float* Wc   = (const float*)d_in[6];
  const float* bc   = (const float*)d_in[7];
  const float* Wh   = (const float*)d_in[8];
  const float* bh   = (const float*)d_in[9];
  float* out = (float*)d_out;
  char* ws = (char*)d_ws;
  float* xg           = (float*)(ws);                         // 67108864 B
  unsigned short* qbf = (unsigned short*)(ws + 67108864);     //  8388608 B
  float* kf           = (float*)(ws + 75497472);              //   131072 B
  float* ctx          = (float*)(ws + 75628544);              // 16777216 B

  hipLaunchKernelGGL(xg_kernel,  dim3(512),  dim3(256), 0, stream, x, W_ih, b_ih, b_hh, xg);
  hipLaunchKernelGGL(rbf_kernel, dim3(8192), dim3(256), 0, stream, x, prot, kf);
  hipLaunchKernelGGL(lstm_kernel, dim3(1),   dim3(512), 0, stream, xg, W_hh, b_hh, qbf);
  hipLaunchKernelGGL(attn_kernel, dim3(512), dim3(256), 0, stream, qbf, ctx);
  hipLaunchKernelGGL(mlp_kernel,  dim3(512), dim3(256), 0, stream, ctx, kf, Wc, bc, Wh, bh, out);
}

// Round 10
// 1804.200 us; speedup vs baseline: 1.5538x; 1.5538x over previous
//
#include <hip/hip_runtime.h>
#include <stdint.h>

#define B_ 16
#define S_ 2048
#define F_ 129
#define H_ 128
#define G_ 512   // 4*H

typedef float f32x4 __attribute__((ext_vector_type(4)));
typedef float f32x2 __attribute__((ext_vector_type(2)));
typedef short s16x8 __attribute__((ext_vector_type(8)));
typedef _Float16 f16x8 __attribute__((ext_vector_type(8)));

// LDS-only barrier: waits ds ops, does NOT drain vmcnt (global loads/stores
// stay in flight across it). __syncthreads() emits s_waitcnt vmcnt(0).
#define BAR_LDS() __asm__ volatile("s_waitcnt lgkmcnt(0)\n\ts_barrier" ::: "memory")

__device__ inline unsigned short f2bf(float f) {
  union { float f; unsigned u; } v; v.f = f;
  unsigned u = v.u;
  unsigned r = (u + 0x7FFFu + ((u >> 16) & 1u)) >> 16;
  return (unsigned short)r;
}

__device__ inline float rcp_(float x) { return __builtin_amdgcn_rcpf(x); }

__device__ inline float sigmoid_fast(float x) { return rcp_(1.f + __expf(-x)); }

// branchless tanh: 1 - 2/(1+e^{2x})
__device__ inline float tanh_fast(float x) {
  return 1.f - 2.f * rcp_(1.f + __expf(2.f * x));
}

// ---------------------------------------------------------------------------
// xg[b,s,g] = sum_f x[b,s,f] * W_ih[g,f] + (b_ih[g] + b_hh[g]); OUTPUT f16
// (R10: halves the LSTM's per-CU streaming bytes; |xg|<~4 fits f16 easily).
// ---------------------------------------------------------------------------
__global__ __launch_bounds__(256) void xg_kernel(const float* __restrict__ x,
    const float* __restrict__ W_ih, const float* __restrict__ b_ih,
    const float* __restrict__ b_hh, _Float16* __restrict__ xg) {
  __shared__ __align__(16) float xs[64 * 132];
  __shared__ __align__(16) float ws[32 * 132];
  int tid = threadIdx.x;
  long R0 = (long)blockIdx.x * 64;
  for (int i = tid; i < 64 * 129; i += 256) {
    int r = i / 129, c = i - r * 129;
    xs[r * 132 + c] = x[R0 * 129 + i];
  }
  int cl = tid & 31, rg = tid >> 5;
  int r0 = rg * 8;
  for (int ch = 0; ch < 16; ++ch) {
    __syncthreads();
    for (int i = tid; i < 32 * 129; i += 256) {
      int r = i / 129, c = i - r * 129;
      ws[r * 132 + c] = W_ih[(ch * 32 + r) * 129 + c];
    }
    __syncthreads();
    int gcol = ch * 32 + cl;
    float bias = b_ih[gcol] + b_hh[gcol];
    float acc[8];
    #pragma unroll
    for (int rr = 0; rr < 8; ++rr) acc[rr] = bias;
    const float* wr = &ws[cl * 132];
    #pragma unroll 8
    for (int k = 0; k < 128; k += 4) {
      f32x4 w4 = *(const f32x4*)&wr[k];
      #pragma unroll
      for (int rr = 0; rr < 8; ++rr) {
        f32x4 x4 = *(const f32x4*)&xs[(r0 + rr) * 132 + k];
        acc[rr] += x4.x * w4.x + x4.y * w4.y + x4.z * w4.z + x4.w * w4.w;
      }
    }
    float wl = wr[128];
    #pragma unroll
    for (int rr = 0; rr < 8; ++rr) {
      acc[rr] += xs[(r0 + rr) * 132 + 128] * wl;
      xg[(R0 + r0 + rr) * G_ + gcol] = (_Float16)acc[rr];
    }
  }
}

// ---------------------------------------------------------------------------
// RBF: kf[row] = exp(-sum_f (x-p)^2), one wave per row.
// ---------------------------------------------------------------------------
__global__ __launch_bounds__(256) void rbf_kernel(const float* __restrict__ x,
    const float* __restrict__ p, float* __restrict__ kf) {
  int wave = threadIdx.x >> 6, lane = threadIdx.x & 63;
  long row = (long)blockIdx.x * 4 + wave;
  const float* xr = x + row * F_;
  const float* pr = p + row * F_;
  float ss = 0.f;
  for (int k = lane; k < F_; k += 64) { float d = xr[k] - pr[k]; ss += d * d; }
  #pragma unroll
  for (int off = 32; off; off >>= 1) ss += __shfl_xor(ss, off, 64);
  if (lane == 0) kf[row] = __expf(-ss);
}

// ---------------------------------------------------------------------------
// LSTM scan, round 10: batched-M GEMM (R9) with the bandwidth/layout fixes.
// R9's wall was per-CU HBM: 32 KB/step on ONE CU = 2537 cyc/step (12.9 B/cyc,
// exact match). R10: 4 blocks x 4 batches (traffic /4) + f16 xg (/2) ->
// 4 KB/step/CU ~ 320 cyc, hidden by prefetch.
// M-mapping: batch j on M-row 4j -> C row 4j = quad j, reg 0 -> every lane's
// epilogue owns exactly ONE (batch, unit) pair (balanced; R9 put all epilogue
// on quad 0). A rows m hold h[batch m>>2] (duplicates, no garbage).
// hbuf stride 144 halfs (72 dwords = 8 mod 32) -> <=2-way bank aliasing on
// A-frag b128 reads = free (R9's stride-136 was 8-way: 128 conflicts/step).
// Weights resident f16 (16 MFMA/wave/step); BAR_LDS; delayed qbf stores.
// ---------------------------------------------------------------------------
__global__ __launch_bounds__(512, 2) void lstm_kernel(const _Float16* __restrict__ xg,
    const float* __restrict__ W_hh, const float* __restrict__ b_hh,
    unsigned short* __restrict__ qbf) {
  __shared__ __align__(16) _Float16 hbuf[2][4 * 144];   // [dbuf][batch*144 + unit]
  int tid = threadIdx.x;
  int w = tid >> 6, lane = tid & 63;
  int n16 = lane & 15;               // unit col within tile; A-row m
  int q8 = lane >> 4;                // quad: A k-chunk; epilogue batch
  int ab = n16 >> 2;                 // batch whose h this lane READS for A
  int u = (w << 4) | n16;            // unit 0..127
  int bb = blockIdx.x * 4;           // batches bb..bb+3
  (void)b_hh;                        // folded into xg
  // resident weights, f16: Wf[ty][kb] = W_hh[(ty*128+u)][kb*32+q8*8 .. +8]
  f16x8 Wf[4][4];
  #pragma unroll
  for (int ty = 0; ty < 4; ++ty) {
    #pragma unroll
    for (int kb = 0; kb < 4; ++kb) {
      const float* src = &W_hh[(ty * 128 + u) * H_ + kb * 32 + q8 * 8];
      f16x8 v;
      #pragma unroll
      for (int j = 0; j < 8; ++j) v[j] = (_Float16)src[j];
      Wf[ty][kb] = v;
    }
  }
  for (int i = tid; i < 2 * 4 * 144; i += 512)
    ((_Float16*)hbuf)[i] = (_Float16)0.f;    // h_{-1}=0
  float c = 0.f;                      // cell state of (batch bb+q8, unit u)
  const _Float16* xb = xg + (long)(bb + q8) * S_ * G_ + u;
  unsigned short* qb = qbf + (long)(bb + q8) * S_ * H_ + u;
  float cur[4], nxt[4];
  #pragma unroll
  for (int ty = 0; ty < 4; ++ty) {
    cur[ty] = (float)xb[ty * 128];
    nxt[ty] = (float)xb[G_ + ty * 128];
  }
  unsigned short hvp = 0;
  __syncthreads();                   // init visibility (once)
  for (int t = 0; t < S_; ++t) {
    BAR_LDS();                       // h_{t-1} LDS writes visible; no vm drain
    // A-frags: A[m][k] = h[batch m>>2][k]; lane reads m=n16 -> batch ab,
    // k = q8*8 + kb*32 + j.  <=2-way bank aliasing (stride 144 halfs).
    const _Float16* hsrc = hbuf[(t + 1) & 1];
    f16x8 A[4];
    #pragma unroll
    for (int kb = 0; kb < 4; ++kb)
      A[kb] = *(const f16x8*)(hsrc + ab * 144 + kb * 32 + q8 * 8);
    if (t > 0)                       // delayed store: full step in flight
      qb[(long)(t - 1) * H_] = hvp;
    long pf = (long)((t + 2 < S_) ? t + 2 : S_ - 1) * G_;
    float nn[4];
    #pragma unroll
    for (int ty = 0; ty < 4; ++ty) nn[ty] = (float)xb[pf + ty * 128];
    // 4 chained MFMAs per gate type (R8: forced-independent regresses)
    f32x4 acc[4];
    #pragma unroll
    for (int ty = 0; ty < 4; ++ty) {
      f32x4 a;
      a[0] = 0.f; a[1] = 0.f; a[2] = 0.f; a[3] = 0.f;
      #pragma unroll
      for (int kb = 0; kb < 4; ++kb)
        a = __builtin_amdgcn_mfma_f32_16x16x32_f16(A[kb], Wf[ty][kb], a, 0, 0, 0);
      acc[ty] = a;
    }
    // epilogue: C row 4*q8 (batch bb+q8) = this quad's reg 0; col n16 = u.
    float g0 = acc[0][0] + cur[0];
    float g1 = acc[1][0] + cur[1];
    float g2 = acc[2][0] + cur[2];
    float g3 = acc[3][0] + cur[3];
    float ai = sigmoid_fast(g0);
    float af = sigmoid_fast(g1);
    float ag = tanh_fast(g2);
    float ao = sigmoid_fast(g3);
    c = af * c + ai * ag;
    float hv = ao * tanh_fast(c);
    hbuf[t & 1][q8 * 144 + u] = (_Float16)hv;
    hvp = f2bf(hv);
    #pragma unroll
    for (int ty = 0; ty < 4; ++ty) { cur[ty] = nxt[ty]; nxt[ty] = nn[ty]; }
  }
  qb[(long)(S_ - 1) * H_] = hvp;
}

// ---------------------------------------------------------------------------
// Flash attention, scale 1/sqrt(129). 64 Q-rows per block (4 waves x 16 rows),
// KV tiles of 64, bf16 MFMA 16x16x32. Grid = 16 batches * 32 q-tiles.
// ---------------------------------------------------------------------------
__global__ __launch_bounds__(256) void attn_kernel(const unsigned short* __restrict__ qbf,
    float* __restrict__ ctx) {
  __shared__ __align__(16) unsigned short Ks[64 * 136];
  __shared__ __align__(16) unsigned short VT[128 * 72];
  __shared__ __align__(16) unsigned short Ps[4 * 16 * 72];
  int tid = threadIdx.x;
  int lane = tid & 63, w = tid >> 6;
  int b = blockIdx.x >> 5;
  int q0 = (blockIdx.x & 31) * 64;
  const unsigned short* qb = qbf + (long)b * S_ * H_;
  int l15 = lane & 15;
  int koff = (lane >> 4) * 8;
  s16x8 qfrag[4];
  #pragma unroll
  for (int kb = 0; kb < 4; ++kb)
    qfrag[kb] = *(const s16x8*)(qb + (long)(q0 + w * 16 + l15) * H_ + kb * 32 + koff);
  f32x4 oacc[8];
  #pragma unroll
  for (int n = 0; n < 8; ++n)
    #pragma unroll
    for (int r = 0; r < 4; ++r) oacc[n][r] = 0.f;
  float mrow[4], lrow[4];
  #pragma unroll
  for (int r = 0; r < 4; ++r) { mrow[r] = -1e30f; lrow[r] = 0.f; }
  const float scale = 0.08804509063256238f;  // 1/sqrt(129)
  unsigned short* Pw = &Ps[w * 16 * 72];
  for (int t = 0; t < S_ / 64; ++t) {
    {
      int rr = tid >> 4;
      int c0 = (tid & 15) * 8;
      #pragma unroll
      for (int pch = 0; pch < 4; ++pch) {
        int r = pch * 16 + rr;
        s16x8 v = *(const s16x8*)(qb + (long)(t * 64 + r) * H_ + c0);
        *(s16x8*)(&Ks[r * 136 + c0]) = v;
        #pragma unroll
        for (int i = 0; i < 8; ++i) VT[(c0 + i) * 72 + r] = (unsigned short)v[i];
      }
    }
    __syncthreads();
    f32x4 sacc[4];
    #pragma unroll
    for (int n = 0; n < 4; ++n) {
      f32x4 acc;
      #pragma unroll
      for (int r = 0; r < 4; ++r) acc[r] = 0.f;
      #pragma unroll
      for (int kb = 0; kb < 4; ++kb) {
        s16x8 bfrag = *(const s16x8*)(&Ks[(n * 16 + l15) * 136 + kb * 32 + koff]);
        acc = __builtin_amdgcn_mfma_f32_16x16x32_bf16(qfrag[kb], bfrag, acc, 0, 0, 0);
      }
      sacc[n] = acc;
    }
    #pragma unroll
    for (int r = 0; r < 4; ++r) {
      float mx = fmaxf(fmaxf(sacc[0][r], sacc[1][r]), fmaxf(sacc[2][r], sacc[3][r]));
      #pragma unroll
      for (int m = 1; m < 16; m <<= 1) mx = fmaxf(mx, __shfl_xor(mx, m, 64));
      mx *= scale;
      float mnew = fmaxf(mrow[r], mx);
      float alpha = __expf(mrow[r] - mnew);
      mrow[r] = mnew;
      float psum = 0.f;
      #pragma unroll
      for (int n = 0; n < 4; ++n) {
        float pv = __expf(sacc[n][r] * scale - mnew);
        sacc[n][r] = pv;
        psum += pv;
      }
      #pragma unroll
      for (int m = 1; m < 16; m <<= 1) psum += __shfl_xor(psum, m, 64);
      lrow[r] = lrow[r] * alpha + psum;
      #pragma unroll
      for (int n = 0; n < 8; ++n) oacc[n][r] *= alpha;
    }
    #pragma unroll
    for (int n = 0; n < 4; ++n)
      #pragma unroll
      for (int r = 0; r < 4; ++r)
        Pw[((lane >> 4) * 4 + r) * 72 + n * 16 + l15] = f2bf(sacc[n][r]);
    __syncthreads();
    #pragma unroll
    for (int kb = 0; kb < 2; ++kb) {
      s16x8 afrag = *(const s16x8*)(&Pw[l15 * 72 + kb * 32 + koff]);
      #pragma unroll
      for (int n = 0; n < 8; ++n) {
        s16x8 bfrag = *(const s16x8*)(&VT[(n * 16 + l15) * 72 + kb * 32 + koff]);
        oacc[n] = __builtin_amdgcn_mfma_f32_16x16x32_bf16(afrag, bfrag, oacc[n], 0, 0, 0);
      }
    }
    __syncthreads();
  }
  float* cb = ctx + (long)b * S_ * H_;
  #pragma unroll
  for (int n = 0; n < 8; ++n)
    #pragma unroll
    for (int r = 0; r < 4; ++r) {
      int row = q0 + w * 16 + (lane >> 4) * 4 + r;
      cb[(long)row * H_ + n * 16 + l15] = oacc[n][r] / lrow[r];
    }
}

// ---------------------------------------------------------------------------
// Fused MLP: h0=[ctx,kf] -> 4x relu(h W^T + b) -> logits -> log_softmax.
// ---------------------------------------------------------------------------
__global__ __launch_bounds__(256) void mlp_kernel(const float* __restrict__ ctx,
    const float* __restrict__ kf, const float* __restrict__ Wc,
    const float* __restrict__ bc, const float* __restrict__ Wh,
    const float* __restrict__ bh, float* __restrict__ out) {
  __shared__ __align__(16) float hb[64 * 132];
  __shared__ __align__(16) float wc[32 * 132];
  int tid = threadIdx.x;
  long R0 = (long)blockIdx.x * 64;
  for (int i = tid; i < 64 * 128; i += 256) {
    int r = i >> 7, c = i & 127;
    hb[r * 132 + c] = ctx[(R0 + r) * H_ + c];
  }
  for (int r = tid; r < 64; r += 256) hb[r * 132 + 128] = kf[R0 + r];
  int cl = tid & 31, rg = tid >> 5, r0 = rg * 8;
  for (int l = 0; l < 4; ++l) {
    float areg[5][8];
    #pragma unroll
    for (int cc = 0; cc < 5; ++cc) {
      int cbase = cc * 32;
      int ccnt = (cc < 4) ? 32 : 1;
      __syncthreads();
      for (int i = tid; i < ccnt * 129; i += 256) {
        int r = i / 129, c = i - r * 129;
        wc[r * 132 + c] = Wc[(l * 129 + cbase + r) * 129 + c];
      }
      __syncthreads();
      if (cl < ccnt) {
        float bias = bc[l * 129 + cbase + cl];
        float acc[8];
        #pragma unroll
        for (int rr = 0; rr < 8; ++rr) acc[rr] = bias;
        const float* wr = &wc[cl * 132];
        for (int k = 0; k < 128; k += 4) {
          f32x4 w4 = *(const f32x4*)&wr[k];
          #pragma unroll
          for (int rr = 0; rr < 8; ++rr) {
            f32x4 x4 = *(const f32x4*)&hb[(r0 + rr) * 132 + k];
            acc[rr] += x4.x * w4.x + x4.y * w4.y + x4.z * w4.z + x4.w * w4.w;
          }
        }
        float wl = wr[128];
        #pragma unroll
        for (int rr = 0; rr < 8; ++rr)
          areg[cc][rr] = fmaxf(acc[rr] + hb[(r0 + rr) * 132 + 128] * wl, 0.f);
      }
    }
    __syncthreads();
    #pragma unroll
    for (int cc = 0; cc < 5; ++cc) {
      int ccnt = (cc < 4) ? 32 : 1;
      if (cl < ccnt) {
        #pragma unroll
        for (int rr = 0; rr < 8; ++rr) hb[(r0 + rr) * 132 + cc * 32 + cl] = areg[cc][rr];
      }
    }
    __syncthreads();
  }
  if (tid < 64) {
    int r = tid;
    float z0 = bh[0], z1 = bh[1];
    for (int k = 0; k < 129; ++k) {
      float h = hb[r * 132 + k];
      z0 += h * Wh[k];
      z1 += h * Wh[129 + k];
    }
    float mx = fmaxf(z0, z1);
    float lse = mx + __logf(__expf(z0 - mx) + __expf(z1 - mx));
    out[(R0 + r) * 2 + 0] = z0 - lse;
    out[(R0 + r) * 2 + 1] = z1 - lse;
  }
}

extern "C" void kernel_launch(void* const* d_in, const int* in_sizes, int n_in,
                              void* d_out, int out_size, void* d_ws, size_t ws_size,
                              hipStream_t stream) {
  const float* x    = (const float*)d_in[0];
  const float* prot = (const float*)d_in[1];
  const float* W_ih = (const float*)d_in[2];
  const float* W_hh = (const float*)d_in[3];
  const float* b_ih = (const float*)d_in[4];
  const float* b_hh = (const float*)d_in[5];
  const float* Wc   = (const float*)d_in[6];
  const float* bc   = (const float*)d_in[7];
  const float* Wh   = (const float*)d_in[8];
  const float* bh   = (const float*)d_in[9];
  float* out = (float*)d_out;
  char* ws = (char*)d_ws;
  _Float16* xgh       = (_Float16*)(ws);                      // 16*2048*512*2 = 33554432
  unsigned short* qbf = (unsigned short*)(ws + 33554432);     //  8388608 B
  float* kf           = (float*)(ws + 41943040);              //   131072 B
  float* ctx          = (float*)(ws + 42074112);              // 16777216 B

  hipLaunchKernelGGL(xg_kernel,  dim3(512),  dim3(256), 0, stream, x, W_ih, b_ih, b_hh, xgh);
  hipLaunchKernelGGL(rbf_kernel, dim3(8192), dim3(256), 0, stream, x, prot, kf);
  hipLaunchKernelGGL(lstm_kernel, dim3(4),   dim3(512), 0, stream, xgh, W_hh, b_hh, qbf);
  hipLaunchKernelGGL(attn_kernel, dim3(512), dim3(256), 0, stream, qbf, ctx);
  hipLaunchKernelGGL(mlp_kernel,  dim3(512), dim3(256), 0, stream, ctx, kf, Wc, bc, Wh, bh, out);
}

// Round 11
// 1539.418 us; speedup vs baseline: 1.8210x; 1.1720x over previous
//
#include <hip/hip_runtime.h>
#include <stdint.h>

#define B_ 16
#define S_ 2048
#define F_ 129
#define H_ 128
#define G_ 512   // 4*H

typedef float f32x4 __attribute__((ext_vector_type(4)));
typedef float f32x2 __attribute__((ext_vector_type(2)));
typedef short s16x8 __attribute__((ext_vector_type(8)));
typedef _Float16 f16x8 __attribute__((ext_vector_type(8)));
typedef _Float16 f16x4 __attribute__((ext_vector_type(4)));

// LDS-only barrier: waits ds ops, does NOT drain vmcnt (global loads/stores
// stay in flight across it). __syncthreads() emits s_waitcnt vmcnt(0).
#define BAR_LDS() __asm__ volatile("s_waitcnt lgkmcnt(0)\n\ts_barrier" ::: "memory")

__device__ inline unsigned short h2bits(_Float16 h) {
  union { _Float16 h; unsigned short u; } v; v.h = h; return v.u;
}
__device__ inline unsigned short f2h(float f) { return h2bits((_Float16)f); }

__device__ inline float rcp_(float x) { return __builtin_amdgcn_rcpf(x); }

__device__ inline float sigmoid_fast(float x) { return rcp_(1.f + __expf(-x)); }

// branchless tanh: 1 - 2/(1+e^{2x})
__device__ inline float tanh_fast(float x) {
  return 1.f - 2.f * rcp_(1.f + __expf(2.f * x));
}

// ---------------------------------------------------------------------------
// xg[b,s,u,ty] = sum_f x[b,s,f] * W_ih[ty*128+u,f] + (b_ih + b_hh)[ty*128+u]
// f16 output, GATE-INTERLEAVED inner dim (R11): the LSTM lane's 4 gate values
// are contiguous -> one 8B load/step instead of 4 scattered ushort loads.
// ---------------------------------------------------------------------------
__global__ __launch_bounds__(256) void xg_kernel(const float* __restrict__ x,
    const float* __restrict__ W_ih, const float* __restrict__ b_ih,
    const float* __restrict__ b_hh, _Float16* __restrict__ xg) {
  __shared__ __align__(16) float xs[64 * 132];
  __shared__ __align__(16) float ws[32 * 132];
  int tid = threadIdx.x;
  long R0 = (long)blockIdx.x * 64;
  for (int i = tid; i < 64 * 129; i += 256) {
    int r = i / 129, c = i - r * 129;
    xs[r * 132 + c] = x[R0 * 129 + i];
  }
  int cl = tid & 31, rg = tid >> 5;
  int r0 = rg * 8;
  for (int ch = 0; ch < 16; ++ch) {
    __syncthreads();
    for (int i = tid; i < 32 * 129; i += 256) {
      int r = i / 129, c = i - r * 129;
      ws[r * 132 + c] = W_ih[(ch * 32 + r) * 129 + c];
    }
    __syncthreads();
    int gcol = ch * 32 + cl;
    float bias = b_ih[gcol] + b_hh[gcol];
    float acc[8];
    #pragma unroll
    for (int rr = 0; rr < 8; ++rr) acc[rr] = bias;
    const float* wr = &ws[cl * 132];
    #pragma unroll 8
    for (int k = 0; k < 128; k += 4) {
      f32x4 w4 = *(const f32x4*)&wr[k];
      #pragma unroll
      for (int rr = 0; rr < 8; ++rr) {
        f32x4 x4 = *(const f32x4*)&xs[(r0 + rr) * 132 + k];
        acc[rr] += x4.x * w4.x + x4.y * w4.y + x4.z * w4.z + x4.w * w4.w;
      }
    }
    float wl = wr[128];
    int uo = (gcol & 127) * 4 + (gcol >> 7);   // interleaved index
    #pragma unroll
    for (int rr = 0; rr < 8; ++rr) {
      acc[rr] += xs[(r0 + rr) * 132 + 128] * wl;
      xg[(R0 + r0 + rr) * G_ + uo] = (_Float16)acc[rr];
    }
  }
}

// ---------------------------------------------------------------------------
// RBF: kf[row] = exp(-sum_f (x-p)^2), one wave per row.
// ---------------------------------------------------------------------------
__global__ __launch_bounds__(256) void rbf_kernel(const float* __restrict__ x,
    const float* __restrict__ p, float* __restrict__ kf) {
  int wave = threadIdx.x >> 6, lane = threadIdx.x & 63;
  long row = (long)blockIdx.x * 4 + wave;
  const float* xr = x + row * F_;
  const float* pr = p + row * F_;
  float ss = 0.f;
  for (int k = lane; k < F_; k += 64) { float d = xr[k] - pr[k]; ss += d * d; }
  #pragma unroll
  for (int off = 32; off; off >>= 1) ss += __shfl_xor(ss, off, 64);
  if (lane == 0) kf[row] = __expf(-ss);
}

// ---------------------------------------------------------------------------
// LSTM scan, round 11. R10 batched-M GEMM (4 blocks x 4 batches, balanced
// epilogue, stride-144 hbuf, BAR_LDS, delayed q store) plus:
//  (1) t-loop unrolled x4, prefetch ring distance 4 -> a load's first use is
//      ~4000 cyc after issue; kills R10's per-step vmcnt stall on the
//      cur=nxt register shuffle (load issued and waited in the SAME step).
//  (2) gate-interleaved f16 xg: one 8B f16x4 load/lane/step (was 4 ushort).
//  (3) ty-chains split depth4 -> 2 x depth2 + 1 v_add on the single live
//      C-reg (reg 0): 8-way MFMA ILP vs 4 (R10 MfmaUtil showed 15.7
//      cyc/MFMA = chain-latency-bound).
//  (4) h published as f16 bits straight to qbf (no f2bf); attention uses
//      f16 MFMA (same fragment layout; more mantissa than bf16).
// ---------------------------------------------------------------------------
__global__ __launch_bounds__(512, 2) void lstm_kernel(const _Float16* __restrict__ xg,
    const float* __restrict__ W_hh, unsigned short* __restrict__ qbf) {
  __shared__ __align__(16) _Float16 hbuf[2][4 * 144];   // [dbuf][batch*144 + unit]
  int tid = threadIdx.x;
  int w = tid >> 6, lane = tid & 63;
  int n16 = lane & 15;               // unit col within tile; A-row m
  int q8 = lane >> 4;                // quad: A k-chunk; epilogue batch
  int ab = n16 >> 2;                 // batch whose h this lane READS for A
  int u = (w << 4) | n16;            // unit 0..127
  int bb = blockIdx.x * 4;           // batches bb..bb+3
  // resident weights, f16: Wf[ty][kb] = W_hh[(ty*128+u)][kb*32+q8*8 .. +8]
  f16x8 Wf[4][4];
  #pragma unroll
  for (int ty = 0; ty < 4; ++ty) {
    #pragma unroll
    for (int kb = 0; kb < 4; ++kb) {
      const float* src = &W_hh[(ty * 128 + u) * H_ + kb * 32 + q8 * 8];
      f16x8 v;
      #pragma unroll
      for (int j = 0; j < 8; ++j) v[j] = (_Float16)src[j];
      Wf[ty][kb] = v;
    }
  }
  for (int i = tid; i < 2 * 4 * 144; i += 512)
    ((_Float16*)hbuf)[i] = (_Float16)0.f;    // h_{-1}=0
  float c = 0.f;                      // cell state of (batch bb+q8, unit u)
  const _Float16* xb = xg + (long)(bb + q8) * S_ * G_ + u * 4;
  unsigned short* qb = qbf + (long)(bb + q8) * S_ * H_ + u;
  // prefetch ring, distance 4: cur[p] holds step (t+p)'s 4 gate values
  f16x4 cur[4];
  #pragma unroll
  for (int p = 0; p < 4; ++p) cur[p] = *(const f16x4*)(xb + (long)p * G_);
  unsigned short hvp = 0;
  __syncthreads();                   // init visibility (once)
  for (int t = 0; t < S_; t += 4) {
    #pragma unroll
    for (int p = 0; p < 4; ++p) {
      int step = t + p;
      BAR_LDS();                     // h_{step-1} visible; no vm drain
      const _Float16* hsrc = hbuf[(p + 1) & 1];
      f16x8 A[4];
      #pragma unroll
      for (int kb = 0; kb < 4; ++kb)
        A[kb] = *(const f16x8*)(hsrc + ab * 144 + kb * 32 + q8 * 8);
      if (step > 0)                  // delayed store: full step in flight
        qb[(long)(step - 1) * H_] = hvp;
      f16x4 xcur = cur[p];
      long po = (long)((step + 4 < S_) ? step + 4 : S_ - 1) * G_;
      cur[p] = *(const f16x4*)(xb + po);   // first use: 4 phases from now
      // 8 independent depth-2 MFMA chains; only C-reg 0 is live per lane.
      f32x4 acc0[4], acc1[4];
      #pragma unroll
      for (int ty = 0; ty < 4; ++ty) {
        f32x4 a0, a1;
        a0[0] = 0.f; a0[1] = 0.f; a0[2] = 0.f; a0[3] = 0.f;
        a1 = a0;
        a0 = __builtin_amdgcn_mfma_f32_16x16x32_f16(A[0], Wf[ty][0], a0, 0, 0, 0);
        a1 = __builtin_amdgcn_mfma_f32_16x16x32_f16(A[2], Wf[ty][2], a1, 0, 0, 0);
        a0 = __builtin_amdgcn_mfma_f32_16x16x32_f16(A[1], Wf[ty][1], a0, 0, 0, 0);
        a1 = __builtin_amdgcn_mfma_f32_16x16x32_f16(A[3], Wf[ty][3], a1, 0, 0, 0);
        acc0[ty] = a0; acc1[ty] = a1;
      }
      float g0 = (acc0[0][0] + acc1[0][0]) + (float)xcur[0];
      float g1 = (acc0[1][0] + acc1[1][0]) + (float)xcur[1];
      float g2 = (acc0[2][0] + acc1[2][0]) + (float)xcur[2];
      float g3 = (acc0[3][0] + acc1[3][0]) + (float)xcur[3];
      float ai = sigmoid_fast(g0);
      float af = sigmoid_fast(g1);
      float ag = tanh_fast(g2);
      float ao = sigmoid_fast(g3);
      c = af * c + ai * ag;
      float hv = ao * tanh_fast(c);
      _Float16 hf = (_Float16)hv;
      hbuf[p & 1][q8 * 144 + u] = hf;
      hvp = h2bits(hf);              // qbf now holds f16 bits
    }
  }
  qb[(long)(S_ - 1) * H_] = hvp;
}

// ---------------------------------------------------------------------------
// Flash attention, scale 1/sqrt(129). 64 Q-rows per block (4 waves x 16 rows),
// KV tiles of 64, f16 MFMA 16x16x32 (qbf holds f16 bits since R11).
// Grid = 16 batches * 32 q-tiles.
// ---------------------------------------------------------------------------
__global__ __launch_bounds__(256) void attn_kernel(const unsigned short* __restrict__ qbf,
    float* __restrict__ ctx) {
  __shared__ __align__(16) unsigned short Ks[64 * 136];
  __shared__ __align__(16) unsigned short VT[128 * 72];
  __shared__ __align__(16) unsigned short Ps[4 * 16 * 72];
  int tid = threadIdx.x;
  int lane = tid & 63, w = tid >> 6;
  int b = blockIdx.x >> 5;
  int q0 = (blockIdx.x & 31) * 64;
  const unsigned short* qb = qbf + (long)b * S_ * H_;
  int l15 = lane & 15;
  int koff = (lane >> 4) * 8;
  f16x8 qfrag[4];
  #pragma unroll
  for (int kb = 0; kb < 4; ++kb)
    qfrag[kb] = *(const f16x8*)(qb + (long)(q0 + w * 16 + l15) * H_ + kb * 32 + koff);
  f32x4 oacc[8];
  #pragma unroll
  for (int n = 0; n < 8; ++n)
    #pragma unroll
    for (int r = 0; r < 4; ++r) oacc[n][r] = 0.f;
  float mrow[4], lrow[4];
  #pragma unroll
  for (int r = 0; r < 4; ++r) { mrow[r] = -1e30f; lrow[r] = 0.f; }
  const float scale = 0.08804509063256238f;  // 1/sqrt(129)
  unsigned short* Pw = &Ps[w * 16 * 72];
  for (int t = 0; t < S_ / 64; ++t) {
    {
      int rr = tid >> 4;
      int c0 = (tid & 15) * 8;
      #pragma unroll
      for (int pch = 0; pch < 4; ++pch) {
        int r = pch * 16 + rr;
        s16x8 v = *(const s16x8*)(qb + (long)(t * 64 + r) * H_ + c0);
        *(s16x8*)(&Ks[r * 136 + c0]) = v;
        #pragma unroll
        for (int i = 0; i < 8; ++i) VT[(c0 + i) * 72 + r] = (unsigned short)v[i];
      }
    }
    __syncthreads();
    f32x4 sacc[4];
    #pragma unroll
    for (int n = 0; n < 4; ++n) {
      f32x4 acc;
      #pragma unroll
      for (int r = 0; r < 4; ++r) acc[r] = 0.f;
      #pragma unroll
      for (int kb = 0; kb < 4; ++kb) {
        f16x8 bfrag = *(const f16x8*)(&Ks[(n * 16 + l15) * 136 + kb * 32 + koff]);
        acc = __builtin_amdgcn_mfma_f32_16x16x32_f16(qfrag[kb], bfrag, acc, 0, 0, 0);
      }
      sacc[n] = acc;
    }
    #pragma unroll
    for (int r = 0; r < 4; ++r) {
      float mx = fmaxf(fmaxf(sacc[0][r], sacc[1][r]), fmaxf(sacc[2][r], sacc[3][r]));
      #pragma unroll
      for (int m = 1; m < 16; m <<= 1) mx = fmaxf(mx, __shfl_xor(mx, m, 64));
      mx *= scale;
      float mnew = fmaxf(mrow[r], mx);
      float alpha = __expf(mrow[r] - mnew);
      mrow[r] = mnew;
      float psum = 0.f;
      #pragma unroll
      for (int n = 0; n < 4; ++n) {
        float pv = __expf(sacc[n][r] * scale - mnew);
        sacc[n][r] = pv;
        psum += pv;
      }
      #pragma unroll
      for (int m = 1; m < 16; m <<= 1) psum += __shfl_xor(psum, m, 64);
      lrow[r] = lrow[r] * alpha + psum;
      #pragma unroll
      for (int n = 0; n < 8; ++n) oacc[n][r] *= alpha;
    }
    #pragma unroll
    for (int n = 0; n < 4; ++n)
      #pragma unroll
      for (int r = 0; r < 4; ++r)
        Pw[((lane >> 4) * 4 + r) * 72 + n * 16 + l15] = f2h(sacc[n][r]);
    __syncthreads();
    #pragma unroll
    for (int kb = 0; kb < 2; ++kb) {
      f16x8 afrag = *(const f16x8*)(&Pw[l15 * 72 + kb * 32 + koff]);
      #pragma unroll
      for (int n = 0; n < 8; ++n) {
        f16x8 bfrag = *(const f16x8*)(&VT[(n * 16 + l15) * 72 + kb * 32 + koff]);
        oacc[n] = __builtin_amdgcn_mfma_f32_16x16x32_f16(afrag, bfrag, oacc[n], 0, 0, 0);
      }
    }
    __syncthreads();
  }
  float* cb = ctx + (long)b * S_ * H_;
  #pragma unroll
  for (int n = 0; n < 8; ++n)
    #pragma unroll
    for (int r = 0; r < 4; ++r) {
      int row = q0 + w * 16 + (lane >> 4) * 4 + r;
      cb[(long)row * H_ + n * 16 + l15] = oacc[n][r] / lrow[r];
    }
}

// ---------------------------------------------------------------------------
// Fused MLP: h0=[ctx,kf] -> 4x relu(h W^T + b) -> logits -> log_softmax.
// ---------------------------------------------------------------------------
__global__ __launch_bounds__(256) void mlp_kernel(const float* __restrict__ ctx,
    const float* __restrict__ kf, const float* __restrict__ Wc,
    const float* __restrict__ bc, const float* __restrict__ Wh,
    const float* __restrict__ bh, float* __restrict__ out) {
  __shared__ __align__(16) float hb[64 * 132];
  __shared__ __align__(16) float wc[32 * 132];
  int tid = threadIdx.x;
  long R0 = (long)blockIdx.x * 64;
  for (int i = tid; i < 64 * 128; i += 256) {
    int r = i >> 7, c = i & 127;
    hb[r * 132 + c] = ctx[(R0 + r) * H_ + c];
  }
  for (int r = tid; r < 64; r += 256) hb[r * 132 + 128] = kf[R0 + r];
  int cl = tid & 31, rg = tid >> 5, r0 = rg * 8;
  for (int l = 0; l < 4; ++l) {
    float areg[5][8];
    #pragma unroll
    for (int cc = 0; cc < 5; ++cc) {
      int cbase = cc * 32;
      int ccnt = (cc < 4) ? 32 : 1;
      __syncthreads();
      for (int i = tid; i < ccnt * 129; i += 256) {
        int r = i / 129, c = i - r * 129;
        wc[r * 132 + c] = Wc[(l * 129 + cbase + r) * 129 + c];
      }
      __syncthreads();
      if (cl < ccnt) {
        float bias = bc[l * 129 + cbase + cl];
        float acc[8];
        #pragma unroll
        for (int rr = 0; rr < 8; ++rr) acc[rr] = bias;
        const float* wr = &wc[cl * 132];
        for (int k = 0; k < 128; k += 4) {
          f32x4 w4 = *(const f32x4*)&wr[k];
          #pragma unroll
          for (int rr = 0; rr < 8; ++rr) {
            f32x4 x4 = *(const f32x4*)&hb[(r0 + rr) * 132 + k];
            acc[rr] += x4.x * w4.x + x4.y * w4.y + x4.z * w4.z + x4.w * w4.w;
          }
        }
        float wl = wr[128];
        #pragma unroll
        for (int rr = 0; rr < 8; ++rr)
          areg[cc][rr] = fmaxf(acc[rr] + hb[(r0 + rr) * 132 + 128] * wl, 0.f);
      }
    }
    __syncthreads();
    #pragma unroll
    for (int cc = 0; cc < 5; ++cc) {
      int ccnt = (cc < 4) ? 32 : 1;
      if (cl < ccnt) {
        #pragma unroll
        for (int rr = 0; rr < 8; ++rr) hb[(r0 + rr) * 132 + cc * 32 + cl] = areg[cc][rr];
      }
    }
    __syncthreads();
  }
  if (tid < 64) {
    int r = tid;
    float z0 = bh[0], z1 = bh[1];
    for (int k = 0; k < 129; ++k) {
      float h = hb[r * 132 + k];
      z0 += h * Wh[k];
      z1 += h * Wh[129 + k];
    }
    float mx = fmaxf(z0, z1);
    float lse = mx + __logf(__expf(z0 - mx) + __expf(z1 - mx));
    out[(R0 + r) * 2 + 0] = z0 - lse;
    out[(R0 + r) * 2 + 1] = z1 - lse;
  }
}

extern "C" void kernel_launch(void* const* d_in, const int* in_sizes, int n_in,
                              void* d_out, int out_size, void* d_ws, size_t ws_size,
                              hipStream_t stream) {
  const float* x    = (const float*)d_in[0];
  const float* prot = (const float*)d_in[1];
  const float* W_ih = (const float*)d_in[2];
  const float* W_hh = (const float*)d_in[3];
  const float* b_ih = (const float*)d_in[4];
  const float* b_hh = (const float*)d_in[5];
  const float* Wc   = (const float*)d_in[6];
  const float* bc   = (const float*)d_in[7];
  const float* Wh   = (const float*)d_in[8];
  const float* bh   = (const float*)d_in[9];
  float* out = (float*)d_out;
  char* ws = (char*)d_ws;
  _Float16* xgh       = (_Float16*)(ws);                      // 16*2048*512*2 = 33554432
  unsigned short* qbf = (unsigned short*)(ws + 33554432);     //  8388608 B (f16 bits)
  float* kf           = (float*)(ws + 41943040);              //   131072 B
  float* ctx          = (float*)(ws + 42074112);              // 16777216 B

  hipLaunchKernelGGL(xg_kernel,  dim3(512),  dim3(256), 0, stream, x, W_ih, b_ih, b_hh, xgh);
  hipLaunchKernelGGL(rbf_kernel, dim3(8192), dim3(256), 0, stream, x, prot, kf);
  hipLaunchKernelGGL(lstm_kernel, dim3(4),   dim3(512), 0, stream, xgh, W_hh, qbf);
  hipLaunchKernelGGL(attn_kernel, dim3(512), dim3(256), 0, stream, qbf, ctx);
  hipLaunchKernelGGL(mlp_kernel,  dim3(512), dim3(256), 0, stream, ctx, kf, Wc, bc, Wh, bh, out);
}

// Round 12
// 1485.868 us; speedup vs baseline: 1.8866x; 1.0360x over previous
//
#include <hip/hip_runtime.h>
#include <stdint.h>

#define B_ 16
#define S_ 2048
#define F_ 129
#define H_ 128
#define G_ 512   // 4*H

typedef float f32x4 __attribute__((ext_vector_type(4)));
typedef float f32x2 __attribute__((ext_vector_type(2)));
typedef short s16x8 __attribute__((ext_vector_type(8)));
typedef _Float16 f16x8 __attribute__((ext_vector_type(8)));
typedef _Float16 f16x4 __attribute__((ext_vector_type(4)));

// LDS-only barrier: waits ds ops, does NOT drain vmcnt (global loads/stores
// stay in flight across it). __syncthreads() emits s_waitcnt vmcnt(0).
#define BAR_LDS() __asm__ volatile("s_waitcnt lgkmcnt(0)\n\ts_barrier" ::: "memory")

__device__ inline unsigned short h2bits(_Float16 h) {
  union { _Float16 h; unsigned short u; } v; v.h = h; return v.u;
}
__device__ inline unsigned short f2h(float f) { return h2bits((_Float16)f); }

__device__ inline float rcp_(float x) { return __builtin_amdgcn_rcpf(x); }

__device__ inline float sigmoid_fast(float x) { return rcp_(1.f + __expf(-x)); }

// branchless tanh: 1 - 2/(1+e^{2x})
__device__ inline float tanh_fast(float x) {
  return 1.f - 2.f * rcp_(1.f + __expf(2.f * x));
}

// ---------------------------------------------------------------------------
// xg[b,s,u,ty] = sum_f x[b,s,f] * W_ih[ty*128+u,f] + (b_ih + b_hh)[ty*128+u]
// f16 output, gate-interleaved inner dim (one 8B load/step in the LSTM).
// ---------------------------------------------------------------------------
__global__ __launch_bounds__(256) void xg_kernel(const float* __restrict__ x,
    const float* __restrict__ W_ih, const float* __restrict__ b_ih,
    const float* __restrict__ b_hh, _Float16* __restrict__ xg) {
  __shared__ __align__(16) float xs[64 * 132];
  __shared__ __align__(16) float ws[32 * 132];
  int tid = threadIdx.x;
  long R0 = (long)blockIdx.x * 64;
  for (int i = tid; i < 64 * 129; i += 256) {
    int r = i / 129, c = i - r * 129;
    xs[r * 132 + c] = x[R0 * 129 + i];
  }
  int cl = tid & 31, rg = tid >> 5;
  int r0 = rg * 8;
  for (int ch = 0; ch < 16; ++ch) {
    __syncthreads();
    for (int i = tid; i < 32 * 129; i += 256) {
      int r = i / 129, c = i - r * 129;
      ws[r * 132 + c] = W_ih[(ch * 32 + r) * 129 + c];
    }
    __syncthreads();
    int gcol = ch * 32 + cl;
    float bias = b_ih[gcol] + b_hh[gcol];
    float acc[8];
    #pragma unroll
    for (int rr = 0; rr < 8; ++rr) acc[rr] = bias;
    const float* wr = &ws[cl * 132];
    #pragma unroll 8
    for (int k = 0; k < 128; k += 4) {
      f32x4 w4 = *(const f32x4*)&wr[k];
      #pragma unroll
      for (int rr = 0; rr < 8; ++rr) {
        f32x4 x4 = *(const f32x4*)&xs[(r0 + rr) * 132 + k];
        acc[rr] += x4.x * w4.x + x4.y * w4.y + x4.z * w4.z + x4.w * w4.w;
      }
    }
    float wl = wr[128];
    int uo = (gcol & 127) * 4 + (gcol >> 7);   // interleaved index
    #pragma unroll
    for (int rr = 0; rr < 8; ++rr) {
      acc[rr] += xs[(r0 + rr) * 132 + 128] * wl;
      xg[(R0 + r0 + rr) * G_ + uo] = (_Float16)acc[rr];
    }
  }
}

// ---------------------------------------------------------------------------
// RBF: kf[row] = exp(-sum_f (x-p)^2), one wave per row.
// ---------------------------------------------------------------------------
__global__ __launch_bounds__(256) void rbf_kernel(const float* __restrict__ x,
    const float* __restrict__ p, float* __restrict__ kf) {
  int wave = threadIdx.x >> 6, lane = threadIdx.x & 63;
  long row = (long)blockIdx.x * 4 + wave;
  const float* xr = x + row * F_;
  const float* pr = p + row * F_;
  float ss = 0.f;
  for (int k = lane; k < F_; k += 64) { float d = xr[k] - pr[k]; ss += d * d; }
  #pragma unroll
  for (int off = 32; off; off >>= 1) ss += __shfl_xor(ss, off, 64);
  if (lane == 0) kf[row] = __expf(-ss);
}

// ---------------------------------------------------------------------------
// LSTM scan, round 12 = R11 structure (4 blocks x 4 batches, batched-M GEMM,
// stride-144 hbuf, BAR_LDS, delayed q store, x4 unroll + distance-4 prefetch
// ring, 2x depth-2 MFMA chains) with a pure VALU-issue trim -- R11 counters
// showed MFMA pipe 620 cyc/step (the structural floor: 128 MFMA/CU/step x
// 4.85 cyc) + ~500 cyc serialized VALU = 1085 wall:
//  (1) strength-reduced addressing: running pointers qp/xpf, no per-step
//      64-bit mults, tail clamp dropped (prefetch overrun lands in the
//      adjacent ws region, loaded-but-never-used).
//  (2) xg folded into the MFMA C-input: C-reg 0 (the only live element)
//      initialized with xcur[ty] -> kills 4 v_add + merges 4 cvt.
//  (3) store guard t+p>0 is compile-time-true for 3 of 4 phases.
//  (4) per-buffer A-frag base pointers -> immediate-offset ds_read_b128.
// ---------------------------------------------------------------------------
__global__ __launch_bounds__(512, 2) void lstm_kernel(const _Float16* __restrict__ xg,
    const float* __restrict__ W_hh, unsigned short* __restrict__ qbf) {
  __shared__ __align__(16) _Float16 hbuf[2][4 * 144];   // [dbuf][batch*144 + unit]
  int tid = threadIdx.x;
  int w = tid >> 6, lane = tid & 63;
  int n16 = lane & 15;               // unit col within tile; A-row m
  int q8 = lane >> 4;                // quad: A k-chunk; epilogue batch
  int ab = n16 >> 2;                 // batch whose h this lane READS for A
  int u = (w << 4) | n16;            // unit 0..127
  int bb = blockIdx.x * 4;           // batches bb..bb+3
  // resident weights, f16: Wf[ty][kb] = W_hh[(ty*128+u)][kb*32+q8*8 .. +8]
  f16x8 Wf[4][4];
  #pragma unroll
  for (int ty = 0; ty < 4; ++ty) {
    #pragma unroll
    for (int kb = 0; kb < 4; ++kb) {
      const float* src = &W_hh[(ty * 128 + u) * H_ + kb * 32 + q8 * 8];
      f16x8 v;
      #pragma unroll
      for (int j = 0; j < 8; ++j) v[j] = (_Float16)src[j];
      Wf[ty][kb] = v;
    }
  }
  for (int i = tid; i < 2 * 4 * 144; i += 512)
    ((_Float16*)hbuf)[i] = (_Float16)0.f;    // h_{-1}=0
  float c = 0.f;                      // cell state of (batch bb+q8, unit u)
  int hoff = ab * 144 + q8 * 8;
  const _Float16* h0 = &hbuf[0][hoff];
  const _Float16* h1 = &hbuf[1][hoff];
  _Float16* hw = &hbuf[0][q8 * 144 + u];     // write slot, buffer 0
  const int hstride = 4 * 144;               // halfs between buffers
  const _Float16* xb = xg + (long)(bb + q8) * S_ * G_ + u * 4;
  unsigned short* qp = qbf + (long)(bb + q8) * S_ * H_ + u - H_;  // slot -1
  const _Float16* xpf = xb + 4 * G_;         // prefetch cursor: step 4
  // prefetch ring, distance 4
  f16x4 cur[4];
  #pragma unroll
  for (int p = 0; p < 4; ++p) cur[p] = *(const f16x4*)(xb + (long)p * G_);
  unsigned short hvp = 0;
  __syncthreads();                   // init visibility (once)
  for (int t = 0; t < S_; t += 4) {
    #pragma unroll
    for (int p = 0; p < 4; ++p) {
      BAR_LDS();                     // h_{step-1} visible; no vm drain
      // read buffer (p+1)&1: p even -> buf1, p odd -> buf0
      const _Float16* hsrc = (p & 1) ? h0 : h1;
      f16x8 A[4];
      #pragma unroll
      for (int kb = 0; kb < 4; ++kb)
        A[kb] = *(const f16x8*)(hsrc + kb * 32);
      if (t + p > 0)                 // compile-time true for p>0
        *qp = hvp;
      qp += H_;
      f16x4 xcur = cur[p];
      cur[p] = *(const f16x4*)xpf;   // first use: 4 phases from now
      xpf += G_;
      // 8 depth-2 MFMA chains; C-reg 0 pre-loaded with xg (only live elem).
      f32x4 r0a[4], r1a[4];
      #pragma unroll
      for (int ty = 0; ty < 4; ++ty) {
        f32x4 a0, a1;
        a0[0] = (float)xcur[ty]; a0[1] = 0.f; a0[2] = 0.f; a0[3] = 0.f;
        a1[0] = 0.f; a1[1] = 0.f; a1[2] = 0.f; a1[3] = 0.f;
        a0 = __builtin_amdgcn_mfma_f32_16x16x32_f16(A[0], Wf[ty][0], a0, 0, 0, 0);
        a1 = __builtin_amdgcn_mfma_f32_16x16x32_f16(A[2], Wf[ty][2], a1, 0, 0, 0);
        a0 = __builtin_amdgcn_mfma_f32_16x16x32_f16(A[1], Wf[ty][1], a0, 0, 0, 0);
        a1 = __builtin_amdgcn_mfma_f32_16x16x32_f16(A[3], Wf[ty][3], a1, 0, 0, 0);
        r0a[ty] = a0; r1a[ty] = a1;
      }
      float g0 = r0a[0][0] + r1a[0][0];
      float g1 = r0a[1][0] + r1a[1][0];
      float g2 = r0a[2][0] + r1a[2][0];
      float g3 = r0a[3][0] + r1a[3][0];
      float ai = sigmoid_fast(g0);
      float af = sigmoid_fast(g1);
      float ag = tanh_fast(g2);
      float ao = sigmoid_fast(g3);
      c = af * c + ai * ag;
      float hv = ao * tanh_fast(c);
      _Float16 hf = (_Float16)hv;
      hw[(p & 1) * hstride] = hf;    // write buffer p&1
      hvp = h2bits(hf);
    }
  }
  *qp = hvp;                         // qp = slot S_-1 after the loop
}

// ---------------------------------------------------------------------------
// Flash attention, scale 1/sqrt(129). 64 Q-rows per block (4 waves x 16 rows),
// KV tiles of 64, f16 MFMA 16x16x32 (qbf holds f16 bits).
// Grid = 16 batches * 32 q-tiles.
// ---------------------------------------------------------------------------
__global__ __launch_bounds__(256) void attn_kernel(const unsigned short* __restrict__ qbf,
    float* __restrict__ ctx) {
  __shared__ __align__(16) unsigned short Ks[64 * 136];
  __shared__ __align__(16) unsigned short VT[128 * 72];
  __shared__ __align__(16) unsigned short Ps[4 * 16 * 72];
  int tid = threadIdx.x;
  int lane = tid & 63, w = tid >> 6;
  int b = blockIdx.x >> 5;
  int q0 = (blockIdx.x & 31) * 64;
  const unsigned short* qb = qbf + (long)b * S_ * H_;
  int l15 = lane & 15;
  int koff = (lane >> 4) * 8;
  f16x8 qfrag[4];
  #pragma unroll
  for (int kb = 0; kb < 4; ++kb)
    qfrag[kb] = *(const f16x8*)(qb + (long)(q0 + w * 16 + l15) * H_ + kb * 32 + koff);
  f32x4 oacc[8];
  #pragma unroll
  for (int n = 0; n < 8; ++n)
    #pragma unroll
    for (int r = 0; r < 4; ++r) oacc[n][r] = 0.f;
  float mrow[4], lrow[4];
  #pragma unroll
  for (int r = 0; r < 4; ++r) { mrow[r] = -1e30f; lrow[r] = 0.f; }
  const float scale = 0.08804509063256238f;  // 1/sqrt(129)
  unsigned short* Pw = &Ps[w * 16 * 72];
  for (int t = 0; t < S_ / 64; ++t) {
    {
      int rr = tid >> 4;
      int c0 = (tid & 15) * 8;
      #pragma unroll
      for (int pch = 0; pch < 4; ++pch) {
        int r = pch * 16 + rr;
        s16x8 v = *(const s16x8*)(qb + (long)(t * 64 + r) * H_ + c0);
        *(s16x8*)(&Ks[r * 136 + c0]) = v;
        #pragma unroll
        for (int i = 0; i < 8; ++i) VT[(c0 + i) * 72 + r] = (unsigned short)v[i];
      }
    }
    __syncthreads();
    f32x4 sacc[4];
    #pragma unroll
    for (int n = 0; n < 4; ++n) {
      f32x4 acc;
      #pragma unroll
      for (int r = 0; r < 4; ++r) acc[r] = 0.f;
      #pragma unroll
      for (int kb = 0; kb < 4; ++kb) {
        f16x8 bfrag = *(const f16x8*)(&Ks[(n * 16 + l15) * 136 + kb * 32 + koff]);
        acc = __builtin_amdgcn_mfma_f32_16x16x32_f16(qfrag[kb], bfrag, acc, 0, 0, 0);
      }
      sacc[n] = acc;
    }
    #pragma unroll
    for (int r = 0; r < 4; ++r) {
      float mx = fmaxf(fmaxf(sacc[0][r], sacc[1][r]), fmaxf(sacc[2][r], sacc[3][r]));
      #pragma unroll
      for (int m = 1; m < 16; m <<= 1) mx = fmaxf(mx, __shfl_xor(mx, m, 64));
      mx *= scale;
      float mnew = fmaxf(mrow[r], mx);
      float alpha = __expf(mrow[r] - mnew);
      mrow[r] = mnew;
      float psum = 0.f;
      #pragma unroll
      for (int n = 0; n < 4; ++n) {
        float pv = __expf(sacc[n][r] * scale - mnew);
        sacc[n][r] = pv;
        psum += pv;
      }
      #pragma unroll
      for (int m = 1; m < 16; m <<= 1) psum += __shfl_xor(psum, m, 64);
      lrow[r] = lrow[r] * alpha + psum;
      #pragma unroll
      for (int n = 0; n < 8; ++n) oacc[n][r] *= alpha;
    }
    #pragma unroll
    for (int n = 0; n < 4; ++n)
      #pragma unroll
      for (int r = 0; r < 4; ++r)
        Pw[((lane >> 4) * 4 + r) * 72 + n * 16 + l15] = f2h(sacc[n][r]);
    __syncthreads();
    #pragma unroll
    for (int kb = 0; kb < 2; ++kb) {
      f16x8 afrag = *(const f16x8*)(&Pw[l15 * 72 + kb * 32 + koff]);
      #pragma unroll
      for (int n = 0; n < 8; ++n) {
        f16x8 bfrag = *(const f16x8*)(&VT[(n * 16 + l15) * 72 + kb * 32 + koff]);
        oacc[n] = __builtin_amdgcn_mfma_f32_16x16x32_f16(afrag, bfrag, oacc[n], 0, 0, 0);
      }
    }
    __syncthreads();
  }
  float* cb = ctx + (long)b * S_ * H_;
  #pragma unroll
  for (int n = 0; n < 8; ++n)
    #pragma unroll
    for (int r = 0; r < 4; ++r) {
      int row = q0 + w * 16 + (lane >> 4) * 4 + r;
      cb[(long)row * H_ + n * 16 + l15] = oacc[n][r] / lrow[r];
    }
}

// ---------------------------------------------------------------------------
// Fused MLP: h0=[ctx,kf] -> 4x relu(h W^T + b) -> logits -> log_softmax.
// ---------------------------------------------------------------------------
__global__ __launch_bounds__(256) void mlp_kernel(const float* __restrict__ ctx,
    const float* __restrict__ kf, const float* __restrict__ Wc,
    const float* __restrict__ bc, const float* __restrict__ Wh,
    const float* __restrict__ bh, float* __restrict__ out) {
  __shared__ __align__(16) float hb[64 * 132];
  __shared__ __align__(16) float wc[32 * 132];
  int tid = threadIdx.x;
  long R0 = (long)blockIdx.x * 64;
  for (int i = tid; i < 64 * 128; i += 256) {
    int r = i >> 7, c = i & 127;
    hb[r * 132 + c] = ctx[(R0 + r) * H_ + c];
  }
  for (int r = tid; r < 64; r += 256) hb[r * 132 + 128] = kf[R0 + r];
  int cl = tid & 31, rg = tid >> 5, r0 = rg * 8;
  for (int l = 0; l < 4; ++l) {
    float areg[5][8];
    #pragma unroll
    for (int cc = 0; cc < 5; ++cc) {
      int cbase = cc * 32;
      int ccnt = (cc < 4) ? 32 : 1;
      __syncthreads();
      for (int i = tid; i < ccnt * 129; i += 256) {
        int r = i / 129, c = i - r * 129;
        wc[r * 132 + c] = Wc[(l * 129 + cbase + r) * 129 + c];
      }
      __syncthreads();
      if (cl < ccnt) {
        float bias = bc[l * 129 + cbase + cl];
        float acc[8];
        #pragma unroll
        for (int rr = 0; rr < 8; ++rr) acc[rr] = bias;
        const float* wr = &wc[cl * 132];
        for (int k = 0; k < 128; k += 4) {
          f32x4 w4 = *(const f32x4*)&wr[k];
          #pragma unroll
          for (int rr = 0; rr < 8; ++rr) {
            f32x4 x4 = *(const f32x4*)&hb[(r0 + rr) * 132 + k];
            acc[rr] += x4.x * w4.x + x4.y * w4.y + x4.z * w4.z + x4.w * w4.w;
          }
        }
        float wl = wr[128];
        #pragma unroll
        for (int rr = 0; rr < 8; ++rr)
          areg[cc][rr] = fmaxf(acc[rr] + hb[(r0 + rr) * 132 + 128] * wl, 0.f);
      }
    }
    __syncthreads();
    #pragma unroll
    for (int cc = 0; cc < 5; ++cc) {
      int ccnt = (cc < 4) ? 32 : 1;
      if (cl < ccnt) {
        #pragma unroll
        for (int rr = 0; rr < 8; ++rr) hb[(r0 + rr) * 132 + cc * 32 + cl] = areg[cc][rr];
      }
    }
    __syncthreads();
  }
  if (tid < 64) {
    int r = tid;
    float z0 = bh[0], z1 = bh[1];
    for (int k = 0; k < 129; ++k) {
      float h = hb[r * 132 + k];
      z0 += h * Wh[k];
      z1 += h * Wh[129 + k];
    }
    float mx = fmaxf(z0, z1);
    float lse = mx + __logf(__expf(z0 - mx) + __expf(z1 - mx));
    out[(R0 + r) * 2 + 0] = z0 - lse;
    out[(R0 + r) * 2 + 1] = z1 - lse;
  }
}

extern "C" void kernel_launch(void* const* d_in, const int* in_sizes, int n_in,
                              void* d_out, int out_size, void* d_ws, size_t ws_size,
                              hipStream_t stream) {
  const float* x    = (const float*)d_in[0];
  const float* prot = (const float*)d_in[1];
  const float* W_ih = (const float*)d_in[2];
  const float* W_hh = (const float*)d_in[3];
  const float* b_ih = (const float*)d_in[4];
  const float* b_hh = (const float*)d_in[5];
  const float* Wc   = (const float*)d_in[6];
  const float* bc   = (const float*)d_in[7];
  const float* Wh   = (const float*)d_in[8];
  const float* bh   = (const float*)d_in[9];
  float* out = (float*)d_out;
  char* ws = (char*)d_ws;
  _Float16* xgh       = (_Float16*)(ws);                      // 16*2048*512*2 = 33554432
  unsigned short* qbf = (unsigned short*)(ws + 33554432);     //  8388608 B (f16 bits)
  float* kf           = (float*)(ws + 41943040);              //   131072 B
  float* ctx          = (float*)(ws + 42074112);              // 16777216 B

  hipLaunchKernelGGL(xg_kernel,  dim3(512),  dim3(256), 0, stream, x, W_ih, b_ih, b_hh, xgh);
  hipLaunchKernelGGL(rbf_kernel, dim3(8192), dim3(256), 0, stream, x, prot, kf);
  hipLaunchKernelGGL(lstm_kernel, dim3(4),   dim3(512), 0, stream, xgh, W_hh, qbf);
  hipLaunchKernelGGL(attn_kernel, dim3(512), dim3(256), 0, stream, qbf, ctx);
  hipLaunchKernelGGL(mlp_kernel,  dim3(512), dim3(256), 0, stream, ctx, kf, Wc, bc, Wh, bh, out);
}

// Round 13
// 1293.831 us; speedup vs baseline: 2.1667x; 1.1484x over previous
//
#include <hip/hip_runtime.h>
#include <stdint.h>

#define B_ 16
#define S_ 2048
#define F_ 129
#define H_ 128
#define G_ 512   // 4*H

typedef float f32x4 __attribute__((ext_vector_type(4)));
typedef float f32x2 __attribute__((ext_vector_type(2)));
typedef short s16x8 __attribute__((ext_vector_type(8)));
typedef _Float16 f16x8 __attribute__((ext_vector_type(8)));
typedef _Float16 f16x4 __attribute__((ext_vector_type(4)));

// LDS-only barrier: waits ds ops, does NOT drain vmcnt.
#define BAR_LDS() __asm__ volatile("s_waitcnt lgkmcnt(0)\n\ts_barrier" ::: "memory")

__device__ inline unsigned short h2bits(_Float16 h) {
  union { _Float16 h; unsigned short u; } v; v.h = h; return v.u;
}
__device__ inline unsigned short f2h(float f) { return h2bits((_Float16)f); }

__device__ inline float rcp_(float x) { return __builtin_amdgcn_rcpf(x); }

__device__ inline float sigmoid_fast(float x) { return rcp_(1.f + __expf(-x)); }

// branchless tanh: 1 - 2/(1+e^{2x})
__device__ inline float tanh_fast(float x) {
  return 1.f - 2.f * rcp_(1.f + __expf(2.f * x));
}

// ---------------------------------------------------------------------------
// xg round 13: f16 MFMA GEMM, transpose-free mapping C[m=gate][n=row].
// A = W_ih rows (row-major), B = x stored [row][k] (row-major) -- both frag
// reads are contiguous b128 at stride 136 halfs (uniform bank load).
// K=129 = 4x32 MFMA + rank-1 (k=128) in the epilogue. Gate-chunk c (=ty)
// accumulated in registers across 4 chunks -> one b64 store per (tile,r)
// preserving the gate-interleaved layout xg[row][unit*4+ty].
// R12 diagnosis: old scalar-FMA version was LDS-read bound (~185 us); this
// is ~512 MFMA/block ~ 2.5K cyc/CU.
// ---------------------------------------------------------------------------
__global__ __launch_bounds__(256) void xg_kernel(const float* __restrict__ x,
    const float* __restrict__ W_ih, const float* __restrict__ b_ih,
    const float* __restrict__ b_hh, _Float16* __restrict__ xg) {
  __shared__ __align__(16) _Float16 xs[64][136];
  __shared__ __align__(16) _Float16 ws[128][136];
  __shared__ float bsum[512];
  int tid = threadIdx.x;
  int lane = tid & 63, w = tid >> 6;
  int l15 = lane & 15, q = lane >> 4;
  long R0 = (long)blockIdx.x * 64;
  // stage x tile f16 (cols 0..127 + col 128)
  for (int it = 0; it < 32; ++it) {
    int i = tid + it * 256;          // 64*128
    int r = i >> 7, c = i & 127;
    xs[r][c] = (_Float16)x[(R0 + r) * 129 + c];
  }
  if (tid < 64) xs[tid][128] = (_Float16)x[(R0 + tid) * 129 + 128];
  for (int it = 0; it < 2; ++it) {
    int g = tid + it * 256;
    bsum[g] = b_ih[g] + b_hh[g];
  }
  __syncthreads();
  // wave's B-frags (rows 16w+l15), constant across chunks
  f16x8 Bf[4];
  #pragma unroll
  for (int kb = 0; kb < 4; ++kb)
    Bf[kb] = *(const f16x8*)&xs[16 * w + l15][kb * 32 + q * 8];
  float x128 = (float)xs[16 * w + l15][128];
  f16x4 res[32];                     // [t*4+r], element c = chunk/ty
  #pragma unroll
  for (int c = 0; c < 4; ++c) {      // gate chunk = ty (MUST unroll: res idx)
    __syncthreads();                 // prior chunk's A-reads done
    for (int it = 0; it < 64; ++it) {
      int i = tid + it * 256;        // 128*128
      int r = i >> 7, cc = i & 127;
      ws[r][cc] = (_Float16)W_ih[(long)(c * 128 + r) * 129 + cc];
    }
    if (tid < 128) ws[tid][128] = (_Float16)W_ih[(long)(c * 128 + tid) * 129 + 128];
    __syncthreads();
    #pragma unroll
    for (int t = 0; t < 8; ++t) {
      f32x4 acc;
      acc[0] = 0.f; acc[1] = 0.f; acc[2] = 0.f; acc[3] = 0.f;
      #pragma unroll
      for (int kb = 0; kb < 4; ++kb) {
        f16x8 Af = *(const f16x8*)&ws[t * 16 + l15][kb * 32 + q * 8];
        acc = __builtin_amdgcn_mfma_f32_16x16x32_f16(Af, Bf[kb], acc, 0, 0, 0);
      }
      #pragma unroll
      for (int r = 0; r < 4; ++r) {
        int unit = t * 16 + q * 4 + r;
        float v = acc[r] + bsum[c * 128 + unit] + x128 * (float)ws[unit][128];
        res[t * 4 + r][c] = (_Float16)v;
      }
    }
  }
  // stores: one b64 per (t,r): units interleaved [unit*4 + ty]
  long rowbase = (R0 + 16 * w + l15) * G_;
  #pragma unroll
  for (int t = 0; t < 8; ++t)
    #pragma unroll
    for (int r = 0; r < 4; ++r)
      *(f16x4*)&xg[rowbase + (t * 16 + q * 4 + r) * 4] = res[t * 4 + r];
}

// ---------------------------------------------------------------------------
// RBF: kf[row] = exp(-sum_f (x-p)^2), one wave per row.
// ---------------------------------------------------------------------------
__global__ __launch_bounds__(256) void rbf_kernel(const float* __restrict__ x,
    const float* __restrict__ p, float* __restrict__ kf) {
  int wave = threadIdx.x >> 6, lane = threadIdx.x & 63;
  long row = (long)blockIdx.x * 4 + wave;
  const float* xr = x + row * F_;
  const float* pr = p + row * F_;
  float ss = 0.f;
  for (int k = lane; k < F_; k += 64) { float d = xr[k] - pr[k]; ss += d * d; }
  #pragma unroll
  for (int off = 32; off; off >>= 1) ss += __shfl_xor(ss, off, 64);
  if (lane == 0) kf[row] = __expf(-ss);
}

// ---------------------------------------------------------------------------
// LSTM scan -- unchanged from R12 (879 us, near the 620-cyc/step MFMA floor).
// ---------------------------------------------------------------------------
__global__ __launch_bounds__(512, 2) void lstm_kernel(const _Float16* __restrict__ xg,
    const float* __restrict__ W_hh, unsigned short* __restrict__ qbf) {
  __shared__ __align__(16) _Float16 hbuf[2][4 * 144];
  int tid = threadIdx.x;
  int w = tid >> 6, lane = tid & 63;
  int n16 = lane & 15;
  int q8 = lane >> 4;
  int ab = n16 >> 2;
  int u = (w << 4) | n16;
  int bb = blockIdx.x * 4;
  f16x8 Wf[4][4];
  #pragma unroll
  for (int ty = 0; ty < 4; ++ty) {
    #pragma unroll
    for (int kb = 0; kb < 4; ++kb) {
      const float* src = &W_hh[(ty * 128 + u) * H_ + kb * 32 + q8 * 8];
      f16x8 v;
      #pragma unroll
      for (int j = 0; j < 8; ++j) v[j] = (_Float16)src[j];
      Wf[ty][kb] = v;
    }
  }
  for (int i = tid; i < 2 * 4 * 144; i += 512)
    ((_Float16*)hbuf)[i] = (_Float16)0.f;
  float c = 0.f;
  int hoff = ab * 144 + q8 * 8;
  const _Float16* h0 = &hbuf[0][hoff];
  const _Float16* h1 = &hbuf[1][hoff];
  _Float16* hw = &hbuf[0][q8 * 144 + u];
  const int hstride = 4 * 144;
  const _Float16* xb = xg + (long)(bb + q8) * S_ * G_ + u * 4;
  unsigned short* qp = qbf + (long)(bb + q8) * S_ * H_ + u - H_;
  const _Float16* xpf = xb + 4 * G_;
  f16x4 cur[4];
  #pragma unroll
  for (int p = 0; p < 4; ++p) cur[p] = *(const f16x4*)(xb + (long)p * G_);
  unsigned short hvp = 0;
  __syncthreads();
  for (int t = 0; t < S_; t += 4) {
    #pragma unroll
    for (int p = 0; p < 4; ++p) {
      BAR_LDS();
      const _Float16* hsrc = (p & 1) ? h0 : h1;
      f16x8 A[4];
      #pragma unroll
      for (int kb = 0; kb < 4; ++kb)
        A[kb] = *(const f16x8*)(hsrc + kb * 32);
      if (t + p > 0)
        *qp = hvp;
      qp += H_;
      f16x4 xcur = cur[p];
      cur[p] = *(const f16x4*)xpf;
      xpf += G_;
      f32x4 r0a[4], r1a[4];
      #pragma unroll
      for (int ty = 0; ty < 4; ++ty) {
        f32x4 a0, a1;
        a0[0] = (float)xcur[ty]; a0[1] = 0.f; a0[2] = 0.f; a0[3] = 0.f;
        a1[0] = 0.f; a1[1] = 0.f; a1[2] = 0.f; a1[3] = 0.f;
        a0 = __builtin_amdgcn_mfma_f32_16x16x32_f16(A[0], Wf[ty][0], a0, 0, 0, 0);
        a1 = __builtin_amdgcn_mfma_f32_16x16x32_f16(A[2], Wf[ty][2], a1, 0, 0, 0);
        a0 = __builtin_amdgcn_mfma_f32_16x16x32_f16(A[1], Wf[ty][1], a0, 0, 0, 0);
        a1 = __builtin_amdgcn_mfma_f32_16x16x32_f16(A[3], Wf[ty][3], a1, 0, 0, 0);
        r0a[ty] = a0; r1a[ty] = a1;
      }
      float g0 = r0a[0][0] + r1a[0][0];
      float g1 = r0a[1][0] + r1a[1][0];
      float g2 = r0a[2][0] + r1a[2][0];
      float g3 = r0a[3][0] + r1a[3][0];
      float ai = sigmoid_fast(g0);
      float af = sigmoid_fast(g1);
      float ag = tanh_fast(g2);
      float ao = sigmoid_fast(g3);
      c = af * c + ai * ag;
      float hv = ao * tanh_fast(c);
      _Float16 hf = (_Float16)hv;
      hw[(p & 1) * hstride] = hf;
      hvp = h2bits(hf);
    }
  }
  *qp = hvp;
}

// ---------------------------------------------------------------------------
// Flash attention -- unchanged from R12. f16 MFMA, qbf holds f16 bits.
// ---------------------------------------------------------------------------
__global__ __launch_bounds__(256) void attn_kernel(const unsigned short* __restrict__ qbf,
    float* __restrict__ ctx) {
  __shared__ __align__(16) unsigned short Ks[64 * 136];
  __shared__ __align__(16) unsigned short VT[128 * 72];
  __shared__ __align__(16) unsigned short Ps[4 * 16 * 72];
  int tid = threadIdx.x;
  int lane = tid & 63, w = tid >> 6;
  int b = blockIdx.x >> 5;
  int q0 = (blockIdx.x & 31) * 64;
  const unsigned short* qb = qbf + (long)b * S_ * H_;
  int l15 = lane & 15;
  int koff = (lane >> 4) * 8;
  f16x8 qfrag[4];
  #pragma unroll
  for (int kb = 0; kb < 4; ++kb)
    qfrag[kb] = *(const f16x8*)(qb + (long)(q0 + w * 16 + l15) * H_ + kb * 32 + koff);
  f32x4 oacc[8];
  #pragma unroll
  for (int n = 0; n < 8; ++n)
    #pragma unroll
    for (int r = 0; r < 4; ++r) oacc[n][r] = 0.f;
  float mrow[4], lrow[4];
  #pragma unroll
  for (int r = 0; r < 4; ++r) { mrow[r] = -1e30f; lrow[r] = 0.f; }
  const float scale = 0.08804509063256238f;  // 1/sqrt(129)
  unsigned short* Pw = &Ps[w * 16 * 72];
  for (int t = 0; t < S_ / 64; ++t) {
    {
      int rr = tid >> 4;
      int c0 = (tid & 15) * 8;
      #pragma unroll
      for (int pch = 0; pch < 4; ++pch) {
        int r = pch * 16 + rr;
        s16x8 v = *(const s16x8*)(qb + (long)(t * 64 + r) * H_ + c0);
        *(s16x8*)(&Ks[r * 136 + c0]) = v;
        #pragma unroll
        for (int i = 0; i < 8; ++i) VT[(c0 + i) * 72 + r] = (unsigned short)v[i];
      }
    }
    __syncthreads();
    f32x4 sacc[4];
    #pragma unroll
    for (int n = 0; n < 4; ++n) {
      f32x4 acc;
      #pragma unroll
      for (int r = 0; r < 4; ++r) acc[r] = 0.f;
      #pragma unroll
      for (int kb = 0; kb < 4; ++kb) {
        f16x8 bfrag = *(const f16x8*)(&Ks[(n * 16 + l15) * 136 + kb * 32 + koff]);
        acc = __builtin_amdgcn_mfma_f32_16x16x32_f16(qfrag[kb], bfrag, acc, 0, 0, 0);
      }
      sacc[n] = acc;
    }
    #pragma unroll
    for (int r = 0; r < 4; ++r) {
      float mx = fmaxf(fmaxf(sacc[0][r], sacc[1][r]), fmaxf(sacc[2][r], sacc[3][r]));
      #pragma unroll
      for (int m = 1; m < 16; m <<= 1) mx = fmaxf(mx, __shfl_xor(mx, m, 64));
      mx *= scale;
      float mnew = fmaxf(mrow[r], mx);
      float alpha = __expf(mrow[r] - mnew);
      mrow[r] = mnew;
      float psum = 0.f;
      #pragma unroll
      for (int n = 0; n < 4; ++n) {
        float pv = __expf(sacc[n][r] * scale - mnew);
        sacc[n][r] = pv;
        psum += pv;
      }
      #pragma unroll
      for (int m = 1; m < 16; m <<= 1) psum += __shfl_xor(psum, m, 64);
      lrow[r] = lrow[r] * alpha + psum;
      #pragma unroll
      for (int n = 0; n < 8; ++n) oacc[n][r] *= alpha;
    }
    #pragma unroll
    for (int n = 0; n < 4; ++n)
      #pragma unroll
      for (int r = 0; r < 4; ++r)
        Pw[((lane >> 4) * 4 + r) * 72 + n * 16 + l15] = f2h(sacc[n][r]);
    __syncthreads();
    #pragma unroll
    for (int kb = 0; kb < 2; ++kb) {
      f16x8 afrag = *(const f16x8*)(&Pw[l15 * 72 + kb * 32 + koff]);
      #pragma unroll
      for (int n = 0; n < 8; ++n) {
        f16x8 bfrag = *(const f16x8*)(&VT[(n * 16 + l15) * 72 + kb * 32 + koff]);
        oacc[n] = __builtin_amdgcn_mfma_f32_16x16x32_f16(afrag, bfrag, oacc[n], 0, 0, 0);
      }
    }
    __syncthreads();
  }
  float* cb = ctx + (long)b * S_ * H_;
  #pragma unroll
  for (int n = 0; n < 8; ++n)
    #pragma unroll
    for (int r = 0; r < 4; ++r) {
      int row = q0 + w * 16 + (lane >> 4) * 4 + r;
      cb[(long)row * H_ + n * 16 + l15] = oacc[n][r] / lrow[r];
    }
}

// ---------------------------------------------------------------------------
// MLP round 13: f16 MFMA, C[m=out_unit][n=row]. A = Wc rows, B = h[row][k];
// both row-major, no transpose. K=129 via rank-1 epilogue; 129th OUTPUT via
// masked 9th M-tile (weight rows 129..143 duplicate row 128, writes guarded).
// h ping-pongs between two [64][136] f16 buffers; epilogue packs 4 units
// into one b64 LDS write. R12 diagnosis: old fp32 version LDS-bound ~230 us.
// ---------------------------------------------------------------------------
__global__ __launch_bounds__(256) void mlp_kernel(const float* __restrict__ ctx,
    const float* __restrict__ kf, const float* __restrict__ Wc,
    const float* __restrict__ bc, const float* __restrict__ Wh,
    const float* __restrict__ bh, float* __restrict__ out) {
  __shared__ __align__(16) _Float16 hb[2][64][136];
  __shared__ __align__(16) _Float16 wl[144][136];
  __shared__ float bl[144];
  int tid = threadIdx.x;
  int lane = tid & 63, w = tid >> 6;
  int l15 = lane & 15, q = lane >> 4;
  long R0 = (long)blockIdx.x * 64;
  for (int it = 0; it < 32; ++it) {
    int i = tid + it * 256;
    int r = i >> 7, c = i & 127;
    hb[0][r][c] = (_Float16)ctx[(R0 + r) * H_ + c];
  }
  if (tid < 64) hb[0][tid][128] = (_Float16)kf[R0 + tid];
  int cur = 0;
  for (int l = 0; l < 4; ++l) {
    __syncthreads();                 // h writes + prior wl reads done
    for (int it = 0; it < 72; ++it) {
      int i = tid + it * 256;        // 144*128
      int r = i >> 7, c = i & 127;
      int rs = (r < 129) ? r : 128;  // dup row 128 into pad rows (garbage-safe)
      wl[r][c] = (_Float16)Wc[((long)l * 129 + rs) * 129 + c];
    }
    if (tid < 144) {
      int rs = (tid < 129) ? tid : 128;
      wl[tid][128] = (_Float16)Wc[((long)l * 129 + rs) * 129 + 128];
      bl[tid] = bc[l * 129 + rs];
    }
    __syncthreads();
    f16x8 Bf[4];
    #pragma unroll
    for (int kb = 0; kb < 4; ++kb)
      Bf[kb] = *(const f16x8*)&hb[cur][16 * w + l15][kb * 32 + q * 8];
    float h128 = (float)hb[cur][16 * w + l15][128];
    int nxt = cur ^ 1;
    #pragma unroll
    for (int t = 0; t < 9; ++t) {
      f32x4 acc;
      acc[0] = 0.f; acc[1] = 0.f; acc[2] = 0.f; acc[3] = 0.f;
      #pragma unroll
      for (int kb = 0; kb < 4; ++kb) {
        f16x8 Af = *(const f16x8*)&wl[t * 16 + l15][kb * 32 + q * 8];
        acc = __builtin_amdgcn_mfma_f32_16x16x32_f16(Af, Bf[kb], acc, 0, 0, 0);
      }
      f16x4 hv;
      #pragma unroll
      for (int r = 0; r < 4; ++r) {
        int u = t * 16 + q * 4 + r;
        float v = acc[r] + bl[u] + h128 * (float)wl[u][128];
        hv[r] = (_Float16)fmaxf(v, 0.f);
      }
      if (t < 8)
        *(f16x4*)&hb[nxt][16 * w + l15][t * 16 + q * 4] = hv;
      else if (q == 0)
        hb[nxt][16 * w + l15][128] = hv[0];   // only unit 128 is real
    }
    cur ^= 1;
  }
  __syncthreads();
  if (tid < 64) {
    float z0 = bh[0], z1 = bh[1];
    for (int k = 0; k < 129; ++k) {
      float h = (float)hb[cur][tid][k];
      z0 += h * Wh[k];
      z1 += h * Wh[129 + k];
    }
    float mx = fmaxf(z0, z1);
    float lse = mx + __logf(__expf(z0 - mx) + __expf(z1 - mx));
    out[(R0 + tid) * 2 + 0] = z0 - lse;
    out[(R0 + tid) * 2 + 1] = z1 - lse;
  }
}

extern "C" void kernel_launch(void* const* d_in, const int* in_sizes, int n_in,
                              void* d_out, int out_size, void* d_ws, size_t ws_size,
                              hipStream_t stream) {
  const float* x    = (const float*)d_in[0];
  const float* prot = (const float*)d_in[1];
  const float* W_ih = (const float*)d_in[2];
  const float* W_hh = (const float*)d_in[3];
  const float* b_ih = (const float*)d_in[4];
  const float* b_hh = (const float*)d_in[5];
  const float* Wc   = (const float*)d_in[6];
  const float* bc   = (const float*)d_in[7];
  const float* Wh   = (const float*)d_in[8];
  const float* bh   = (const float*)d_in[9];
  float* out = (float*)d_out;
  char* ws = (char*)d_ws;
  _Float16* xgh       = (_Float16*)(ws);                      // 33554432 B
  unsigned short* qbf = (unsigned short*)(ws + 33554432);     //  8388608 B (f16 bits)
  float* kf           = (float*)(ws + 41943040);              //   131072 B
  float* ctx          = (float*)(ws + 42074112);              // 16777216 B

  hipLaunchKernelGGL(xg_kernel,  dim3(512),  dim3(256), 0, stream, x, W_ih, b_ih, b_hh, xgh);
  hipLaunchKernelGGL(rbf_kernel, dim3(8192), dim3(256), 0, stream, x, prot, kf);
  hipLaunchKernelGGL(lstm_kernel, dim3(4),   dim3(512), 0, stream, xgh, W_hh, qbf);
  hipLaunchKernelGGL(attn_kernel, dim3(512), dim3(256), 0, stream, qbf, ctx);
  hipLaunchKernelGGL(mlp_kernel,  dim3(512), dim3(256), 0, stream, ctx, kf, Wc, bc, Wh, bh, out);
}